// Round 7
// baseline (947.689 us; speedup 1.0000x reference)
//
#include <hip/hip_runtime.h>
#include <math.h>

#define THREADS 256
#define BSHIFT 7
#define BSIZE 128  // nodes per bucket

typedef short short8 __attribute__((ext_vector_type(8)));
typedef float f32x4 __attribute__((ext_vector_type(4)));

// bf16 helpers (storage = ushort; RNE pack, exact unpack)
__device__ __forceinline__ unsigned short f2bf(float f) {
  unsigned u = __builtin_bit_cast(unsigned, f);
  return (unsigned short)((u + 0x7FFFu + ((u >> 16) & 1u)) >> 16);
}
__device__ __forceinline__ float bflo(unsigned u) {
  return __builtin_bit_cast(float, u << 16);
}
__device__ __forceinline__ float bfhi(unsigned u) {
  return __builtin_bit_cast(float, u & 0xFFFF0000u);
}
__device__ __forceinline__ unsigned pack2(float x, float y) {
  return (unsigned)f2bf(x) | ((unsigned)f2bf(y) << 16);
}

// ---------------- bucketed CSR build ----------------
// Round-7: replaces k_deg + 3-phase scan + k_fill. k_fill wrote 107MB for a
// 6.4MB col array (random 4B scatters dirty full lines that evict before
// coalescing). Bucketed append makes every write stream sequential-per-bucket:
// active write front = 782 buckets x 64B = 50KB, L2-resident.

// Phase 1: histogram of dst>>BSHIFT, LDS pre-binned (782 cnt, 3KB).
__global__ __launch_bounds__(256) void k_bhist(const int* __restrict__ dst,
                                               int* __restrict__ bcnt, int E, int nbk) {
  __shared__ int h[1024];
  for (int i = threadIdx.x; i < nbk; i += 256) h[i] = 0;
  __syncthreads();
  int stride = gridDim.x * 256;
  for (int e = blockIdx.x * 256 + threadIdx.x; e < E; e += stride)
    atomicAdd(&h[dst[e] >> BSHIFT], 1);
  __syncthreads();
  for (int i = threadIdx.x; i < nbk; i += 256)
    if (h[i]) atomicAdd(&bcnt[i], h[i]);
}

// Phase 2: single-block exclusive scan of bucket counts -> bbase[0..nbk].
__global__ __launch_bounds__(256) void k_bscan(const int* __restrict__ bcnt,
                                               int* __restrict__ bbase, int nbk, int E) {
  __shared__ int sums[256];
  int t = threadIdx.x;
  int vals[4];
  int s = 0;
#pragma unroll
  for (int j = 0; j < 4; ++j) {
    int idx = t * 4 + j;
    vals[j] = (idx < nbk) ? bcnt[idx] : 0;
    s += vals[j];
  }
  sums[t] = s;
  __syncthreads();
  for (int off = 1; off < 256; off <<= 1) {
    int v = (t >= off) ? sums[t - off] : 0;
    __syncthreads();
    if (t >= off) sums[t] += v;
    __syncthreads();
  }
  int run = sums[t] - s;  // exclusive prefix of this thread's chunk
#pragma unroll
  for (int j = 0; j < 4; ++j) {
    int idx = t * 4 + j;
    if (idx < nbk) bbase[idx] = run;
    run += vals[j];
  }
  if (t == 0) bbase[nbk] = E;
}

// Phase 3: scatter edges into bucket regions (append -> sequential per bucket).
__global__ __launch_bounds__(256) void k_bscatter(const int* __restrict__ src,
                                                  const int* __restrict__ dst,
                                                  const int* __restrict__ bbase,
                                                  int* __restrict__ bcur,
                                                  int2* __restrict__ bedge, int E) {
  int e = blockIdx.x * 256 + threadIdx.x;
  if (e < E) {
    int d = dst[e];
    int b = d >> BSHIFT;
    int p = atomicAdd(&bcur[b], 1);
    bedge[bbase[b] + p] = make_int2(src[e], d);
  }
}

// Phase 4: one block per bucket — LDS deg/scan/cursor over 128 local nodes,
// coalesced row_ptr write, col scatter confined to an ~8KB L2-local window.
__global__ __launch_bounds__(256) void k_bcsr(const int2* __restrict__ bedge,
                                              const int* __restrict__ bbase,
                                              int* __restrict__ row_ptr,
                                              int* __restrict__ col, int N, int E) {
  int b = blockIdx.x;
  int beg = bbase[b], end = bbase[b + 1];
  int t = threadIdx.x;
  __shared__ int deg[BSIZE];
  __shared__ int offs[BSIZE];
  __shared__ int cur[BSIZE];
  if (t < BSIZE) deg[t] = 0;
  __syncthreads();
  for (int i = beg + t; i < end; i += 256)
    atomicAdd(&deg[bedge[i].y & (BSIZE - 1)], 1);
  __syncthreads();
  if (t < BSIZE) offs[t] = deg[t];
  __syncthreads();
  for (int off = 1; off < BSIZE; off <<= 1) {
    int v = (t < BSIZE && t >= off) ? offs[t - off] : 0;
    __syncthreads();
    if (t < BSIZE && t >= off) offs[t] += v;
    __syncthreads();
  }
  if (t < BSIZE) {
    int node = b * BSIZE + t;
    int ex = beg + offs[t] - deg[t];  // absolute exclusive offset
    if (node < N) row_ptr[node] = ex;
    cur[t] = ex;
  }
  if (b == 0 && t == 0) row_ptr[N] = E;
  __syncthreads();
  for (int i = beg + t; i < end; i += 256) {
    int2 ed = bedge[i];
    int p = atomicAdd(&cur[ed.y & (BSIZE - 1)], 1);
    col[p] = ed.x;
  }
}

// ---------------- fp32 -> bf16 convert (layer-0 X) ----------------
__global__ __launch_bounds__(256) void k_f2bf(const float4* __restrict__ in,
                                              ushort4* __restrict__ out, int n4) {
  int i = blockIdx.x * 256 + threadIdx.x;
  if (i < n4) {
    float4 v = in[i];
    ushort4 o;
    o.x = f2bf(v.x); o.y = f2bf(v.y); o.z = f2bf(v.z); o.w = f2bf(v.w);
    out[i] = o;
  }
}

// ---------------- W pre-swizzle into MFMA A-operand fragment layout ----------------
// Operand swap: A-op = W, B-op = X, so D[m'=C-col][n'=C-row].
// A-op layout (16x16x32): lane holds A[m=lane&15][k=quad*8+j], j=0..7.
__global__ __launch_bounds__(256) void k_wswz(const float* __restrict__ Wl,
                                              const float* __restrict__ Wr,
                                              unsigned short* __restrict__ out) {
  int idx = blockIdx.x * 256 + threadIdx.x;  // 0..32767
  int j = idx & 7, lane = (idx >> 3) & 63, ct = (idx >> 9) & 15, ks = idx >> 13;
  int k = ks * 32 + (lane >> 4) * 8 + j;
  int c = ct * 16 + (lane & 15);
  float v = (c < 128) ? Wl[k * 128 + c] : Wr[k * 128 + (c - 128)];
  out[idx] = f2bf(v);
}

// ---------------- MFMA dual GEMM, D=128, bf16 in/out, fp32 accum ----------------
__global__ __launch_bounds__(256) void gemm128_mfma(
    const unsigned short* __restrict__ Xb, const unsigned short* __restrict__ Wswz,
    const float* __restrict__ bias,
    unsigned short* __restrict__ outL, unsigned short* __restrict__ outR, int M) {
  int wave = threadIdx.x >> 6, lane = threadIdx.x & 63;
  int quad = lane >> 4, n16 = lane & 15;
  int row = blockIdx.x * 64 + wave * 16 + n16;
  int row_ld = min(row, M - 1);
  bool ok = row < M;

  short8 xf[4];
  const unsigned short* xp = Xb + (size_t)row_ld * 128 + quad * 8;
#pragma unroll
  for (int ks = 0; ks < 4; ++ks) xf[ks] = *(const short8*)(xp + ks * 32);

  size_t obase = (size_t)row * 128;
#pragma unroll 4
  for (int ct = 0; ct < 16; ++ct) {
    f32x4 acc = {0.f, 0.f, 0.f, 0.f};
    const unsigned short* wp = Wswz + (size_t)(ct * 64 + lane) * 8;
#pragma unroll
    for (int ks = 0; ks < 4; ++ks) {
      short8 wf = *(const short8*)(wp + ks * 8192);
      acc = __builtin_amdgcn_mfma_f32_16x16x32_bf16(wf, xf[ks], acc, 0, 0, 0);
    }
    int colh = (ct & 7) * 16 + quad * 4;
    if (ct < 8) {
      if (ok) {
        ushort4 o;
        o.x = f2bf(acc[0]); o.y = f2bf(acc[1]); o.z = f2bf(acc[2]); o.w = f2bf(acc[3]);
        *(ushort4*)(outL + obase + colh) = o;
      }
    } else {
      float4 bv = *(const float4*)(bias + colh);
      if (ok) {
        ushort4 o;
        o.x = f2bf(acc[0] + bv.x); o.y = f2bf(acc[1] + bv.y);
        o.z = f2bf(acc[2] + bv.z); o.w = f2bf(acc[3] + bv.w);
        *(ushort4*)(outR + obase + colh) = o;
      }
    }
  }
}

// ---------------- dual GEMM, D=40 (layer 2) — bf16 in, fp32 compute ----------------
// tl (message side) written as bf16 padded to 64 cols (128B aligned rows);
// tr (self side, read once per node) stays fp32.
__global__ __launch_bounds__(256) void dual_gemm40(
    const unsigned short* __restrict__ Xb, const float* __restrict__ Wl,
    const float* __restrict__ Wr, const float* __restrict__ b,
    unsigned short* __restrict__ tlb, float* __restrict__ outR, int M) {
  __shared__ float Xs[128 * 64];
  __shared__ float Wsc[32 * 80];
  int row0 = blockIdx.x * 64;
  int tid = threadIdx.x;

  {
    int rr = tid & 63;
    int kq0 = tid >> 6;
    int row = min(row0 + rr, M - 1);
    const unsigned short* xrow = Xb + (size_t)row * 128;
#pragma unroll
    for (int kq = kq0; kq < 16; kq += 4) {
      uint4 raw = *(const uint4*)(xrow + kq * 8);
      int k = kq * 8;
      Xs[(k + 0) * 64 + rr] = bflo(raw.x);
      Xs[(k + 1) * 64 + rr] = bfhi(raw.x);
      Xs[(k + 2) * 64 + rr] = bflo(raw.y);
      Xs[(k + 3) * 64 + rr] = bfhi(raw.y);
      Xs[(k + 4) * 64 + rr] = bflo(raw.z);
      Xs[(k + 5) * 64 + rr] = bfhi(raw.z);
      Xs[(k + 6) * 64 + rr] = bflo(raw.w);
      Xs[(k + 7) * 64 + rr] = bfhi(raw.w);
    }
  }

  float acc[4][5];
#pragma unroll
  for (int i = 0; i < 4; ++i)
#pragma unroll
    for (int j = 0; j < 5; ++j) acc[i][j] = 0.f;

  int tx = tid & 15, ty = tid >> 4;
  int r0 = ty * 4;
  int c0 = tx * 5;

  for (int kk = 0; kk < 128; kk += 32) {
    __syncthreads();
    for (int i = tid; i < 32 * 80; i += 256) {
      int k = i / 80, c = i - k * 80;
      Wsc[i] = (c < 40) ? Wl[(kk + k) * 40 + c] : Wr[(kk + k) * 40 + (c - 40)];
    }
    __syncthreads();
#pragma unroll 8
    for (int k = 0; k < 32; ++k) {
      const float4 xv = *(const float4*)&Xs[(kk + k) * 64 + r0];
      float xf[4] = {xv.x, xv.y, xv.z, xv.w};
      const float* wp = &Wsc[k * 80 + c0];
#pragma unroll
      for (int j = 0; j < 5; ++j) {
        float w = wp[j];
#pragma unroll
        for (int i = 0; i < 4; ++i) acc[i][j] = fmaf(xf[i], w, acc[i][j]);
      }
    }
  }

#pragma unroll
  for (int j = 0; j < 5; ++j) {
    int c80 = c0 + j;
    bool right = c80 >= 40;
    int c = right ? (c80 - 40) : c80;
    float bias = right ? b[c] : 0.f;
#pragma unroll
    for (int i = 0; i < 4; ++i) {
      int row = row0 + r0 + i;
      if (row < M) {
        if (right) outR[(size_t)row * 40 + c] = acc[i][j] + bias;
        else       tlb[(size_t)row * 64 + c] = f2bf(acc[i][j]);
      }
    }
  }
}

// ---------------- aggregation D=128 (bf16 payload), fused deg_inv+add+relu ----------------
__global__ __launch_bounds__(256) void agg128b(
    const unsigned short* __restrict__ xl, const unsigned short* __restrict__ xr,
    const int* __restrict__ row_ptr, const int* __restrict__ col,
    unsigned short* __restrict__ h, int Nn) {
  int wave = threadIdx.x >> 6;
  int lane = threadIdx.x & 63;
  int n = blockIdx.x * 4 + wave;
  if (n >= Nn) return;
  int beg = row_ptr[n], end = row_ptr[n + 1];
  const unsigned* xlu = (const unsigned*)xl;
  float ax0 = 0.f, ay0 = 0.f, ax1 = 0.f, ay1 = 0.f;
  float ax2 = 0.f, ay2 = 0.f, ax3 = 0.f, ay3 = 0.f;
  int e = beg;
  for (; e + 4 <= end; e += 4) {
    unsigned u0 = xlu[(size_t)col[e] * 64 + lane];
    unsigned u1 = xlu[(size_t)col[e + 1] * 64 + lane];
    unsigned u2 = xlu[(size_t)col[e + 2] * 64 + lane];
    unsigned u3 = xlu[(size_t)col[e + 3] * 64 + lane];
    ax0 += bflo(u0); ay0 += bfhi(u0);
    ax1 += bflo(u1); ay1 += bfhi(u1);
    ax2 += bflo(u2); ay2 += bfhi(u2);
    ax3 += bflo(u3); ay3 += bfhi(u3);
  }
  for (; e < end; ++e) {
    unsigned u = xlu[(size_t)col[e] * 64 + lane];
    ax0 += bflo(u); ay0 += bfhi(u);
  }
  float ax = (ax0 + ax1) + (ax2 + ax3);
  float ay = (ay0 + ay1) + (ay2 + ay3);
  float di = 1.0f / (float)max(end - beg, 1);
  unsigned ur = ((const unsigned*)xr)[(size_t)n * 64 + lane];
  float ox = fmaxf(fmaf(ax, di, bflo(ur)), 0.f);
  float oy = fmaxf(fmaf(ay, di, bfhi(ur)), 0.f);
  ((unsigned*)h)[(size_t)n * 64 + lane] = pack2(ox, oy);
}

// ---------------- aggregation D=40 (bf16 padded-64 payload) + log_softmax ----------------
__global__ __launch_bounds__(256) void agg40_lsm(
    const unsigned short* __restrict__ tlb, const float* __restrict__ tr,
    const int* __restrict__ row_ptr, const int* __restrict__ col,
    float* __restrict__ out, int Nn) {
  int wave = threadIdx.x >> 6;
  int lane = threadIdx.x & 63;
  int half = lane >> 5;   // edge parity this half-wave owns
  int l32 = lane & 31;    // channel-pair index (pairs 0..19 valid)
  int n = blockIdx.x * 4 + wave;
  if (n >= Nn) return;
  int beg = row_ptr[n], end = row_ptr[n + 1];
  const unsigned* tlu = (const unsigned*)tlb;
  float a0x = 0.f, a0y = 0.f, a1x = 0.f, a1y = 0.f;
  int e = beg + half;
  for (; e + 2 < end; e += 4) {
    unsigned u0 = tlu[(size_t)col[e] * 32 + l32];
    unsigned u1 = tlu[(size_t)col[e + 2] * 32 + l32];
    a0x += bflo(u0); a0y += bfhi(u0);
    a1x += bflo(u1); a1y += bfhi(u1);
  }
  if (e < end) {
    unsigned u = tlu[(size_t)col[e] * 32 + l32];
    a0x += bflo(u); a0y += bfhi(u);
  }
  float ax = a0x + a1x;
  float ay = a0y + a1y;
  ax += __shfl_xor(ax, 32);
  ay += __shfl_xor(ay, 32);
  bool valid = l32 < 20;
  float di = 1.0f / (float)max(end - beg, 1);
  float2 rv = valid ? ((const float2*)(tr + (size_t)n * 40))[l32]
                    : make_float2(0.f, 0.f);
  float v0 = valid ? fmaf(ax, di, rv.x) : -INFINITY;
  float v1 = valid ? fmaf(ay, di, rv.y) : -INFINITY;
  float m = fmaxf(v0, v1);
#pragma unroll
  for (int off = 32; off; off >>= 1) m = fmaxf(m, __shfl_xor(m, off));
  float ex = valid ? (expf(v0 - m) + expf(v1 - m)) : 0.f;
  float ssum = ex;
#pragma unroll
  for (int off = 32; off; off >>= 1) ssum += __shfl_xor(ssum, off);
  ssum *= 0.5f;  // both halves contributed identical totals
  float lg = logf(ssum);
  if (half == 0 && valid) {
    float2 o;
    o.x = (v0 - m) - lg;
    o.y = (v1 - m) - lg;
    *(float2*)(out + (size_t)n * 40 + 2 * l32) = o;
  }
}

// ---------------- launcher ----------------

extern "C" void kernel_launch(void* const* d_in, const int* in_sizes, int n_in,
                              void* d_out, int out_size, void* d_ws, size_t ws_size,
                              hipStream_t stream) {
  const float* x   = (const float*)d_in[0];
  const int*   ei  = (const int*)d_in[1];
  const float* Wl0 = (const float*)d_in[2];
  const float* Wr0 = (const float*)d_in[3];
  const float* b0  = (const float*)d_in[4];
  const float* Wl1 = (const float*)d_in[5];
  const float* Wr1 = (const float*)d_in[6];
  const float* b1  = (const float*)d_in[7];
  const float* Wl2 = (const float*)d_in[8];
  const float* Wr2 = (const float*)d_in[9];
  const float* b2  = (const float*)d_in[10];

  int N = in_sizes[0] / 128;
  int E = in_sizes[1] / 2;
  const int* src = ei;
  const int* dst = ei + E;
  int nbk = (N + BSIZE - 1) / BSIZE;  // buckets of 128 nodes

  char* ws = (char*)d_ws;
  size_t off = 0;
  auto alloc = [&](size_t bytes) -> void* {
    void* p = ws + off;
    off += (bytes + 255) & ~(size_t)255;
    return p;
  };
  unsigned short* xb  = (unsigned short*)alloc((size_t)N * 128 * 2);  // bf16 X
  unsigned short* gA  = (unsigned short*)alloc((size_t)N * 128 * 2);  // gemm outL
  unsigned short* gB  = (unsigned short*)alloc((size_t)N * 128 * 2);  // gemm outR
  unsigned short* hC  = (unsigned short*)alloc((size_t)N * 128 * 2);  // agg out
  unsigned short* tlb = (unsigned short*)alloc((size_t)N * 64 * 2);   // l2 msgs, bf16 pad-64
  float* tr           = (float*)alloc((size_t)N * 40 * 4);
  int* row_ptr  = (int*)alloc((size_t)(N + 1) * 4);
  int* col      = (int*)alloc((size_t)E * 4);
  int2* bedge   = (int2*)alloc((size_t)E * 8);
  int* bcnt     = (int*)alloc((size_t)(nbk + 1) * 4);
  int* bbase    = (int*)alloc((size_t)(nbk + 1) * 4);
  int* bcur     = (int*)alloc((size_t)(nbk + 1) * 4);
  unsigned short* wswz0 = (unsigned short*)alloc(32768 * 2);
  unsigned short* wswz1 = (unsigned short*)alloc(32768 * 2);
  (void)ws_size; (void)n_in; (void)out_size;

  hipMemsetAsync(bcnt, 0, (size_t)(nbk + 1) * 4, stream);
  hipMemsetAsync(bcur, 0, (size_t)(nbk + 1) * 4, stream);
  hipMemsetAsync(tlb, 0, (size_t)N * 64 * 2, stream);  // zero the 40..63 pad

  int eb = (E + THREADS - 1) / THREADS;
  k_bhist<<<256, 256, 0, stream>>>(dst, bcnt, E, nbk);
  k_bscan<<<1, 256, 0, stream>>>(bcnt, bbase, nbk, E);
  k_bscatter<<<eb, 256, 0, stream>>>(src, dst, bbase, bcur, bedge, E);
  k_bcsr<<<nbk, 256, 0, stream>>>(bedge, bbase, row_ptr, col, N, E);

  int n4 = N * 32;
  k_f2bf<<<(n4 + 255) / 256, 256, 0, stream>>>((const float4*)x, (ushort4*)xb, n4);
  k_wswz<<<128, 256, 0, stream>>>(Wl0, Wr0, wswz0);
  k_wswz<<<128, 256, 0, stream>>>(Wl1, Wr1, wswz1);

  int gg = (N + 63) / 64;
  int nb = (N + 3) / 4;

  // layer 0
  gemm128_mfma<<<gg, 256, 0, stream>>>(xb, wswz0, b0, gA, gB, N);
  agg128b<<<nb, 256, 0, stream>>>(gA, gB, row_ptr, col, hC, N);
  // layer 1
  gemm128_mfma<<<gg, 256, 0, stream>>>(hC, wswz1, b1, gA, gB, N);
  agg128b<<<nb, 256, 0, stream>>>(gA, gB, row_ptr, col, hC, N);
  // layer 2 (40-dim) + log_softmax
  dual_gemm40<<<gg, 256, 0, stream>>>(hC, Wl2, Wr2, b2, tlb, tr, N);
  agg40_lsm<<<nb, 256, 0, stream>>>(tlb, tr, row_ptr, col, (float*)d_out, N);
}

// Round 8
// 590.274 us; speedup vs baseline: 1.6055x; 1.6055x over previous
//
#include <hip/hip_runtime.h>
#include <math.h>

#define THREADS 256
#define BSHIFT 8
#define BSIZE 256   // nodes per bucket
#define NEB 512     // edge blocks for hist/place

typedef short short8 __attribute__((ext_vector_type(8)));
typedef float f32x4 __attribute__((ext_vector_type(4)));

// bf16 helpers (storage = ushort; RNE pack, exact unpack)
__device__ __forceinline__ unsigned short f2bf(float f) {
  unsigned u = __builtin_bit_cast(unsigned, f);
  return (unsigned short)((u + 0x7FFFu + ((u >> 16) & 1u)) >> 16);
}
__device__ __forceinline__ float bflo(unsigned u) {
  return __builtin_bit_cast(float, u << 16);
}
__device__ __forceinline__ float bfhi(unsigned u) {
  return __builtin_bit_cast(float, u & 0xFFFF0000u);
}
__device__ __forceinline__ unsigned pack2(float x, float y) {
  return (unsigned)f2bf(x) | ((unsigned)f2bf(y) << 16);
}

// ---------------- CSR build: two-pass local-offset binning ----------------
// Round-7 k_bscatter failed (377us): 782 global atomic cursors (2046 edges
// each, serialized + cross-XCD line bounce) and shared write fronts (per-XCD
// L2s not coherent -> partial lines flush; WRITE 78MB for 12.8MB data).
// Round-8: counting-sort placement. Exact (block,bucket) offsets from a
// histogram pass; placement uses LDS cursors only (zero global atomics);
// each (block,bucket) write run ~64B = one line. Final per-bucket CSR pass
// (k_bcsr2) scatters col inside a block-private 16KB window on one CU.

// Phase A: per-block histogram of dst>>BSHIFT. cnt_bm[block*nbk + bucket].
__global__ __launch_bounds__(256) void k_ehist(const int* __restrict__ dst,
                                               int* __restrict__ cnt_bm,
                                               int E, int chunk, int nbk) {
  __shared__ int h[1024];
  int blk = blockIdx.x, t = threadIdx.x;
  for (int i = t; i < nbk; i += 256) h[i] = 0;
  __syncthreads();
  int e0 = blk * chunk, e1 = min(e0 + chunk, E);
  for (int e = e0 + t; e < e1; e += 256) atomicAdd(&h[dst[e] >> BSHIFT], 1);
  __syncthreads();
  for (int i = t; i < nbk; i += 256) cnt_bm[(size_t)blk * nbk + i] = h[i];
}

// Phase B1: per-bucket exclusive scan over the NEB block counts.
// locoff_tm[bucket*NEB + block]; bktot[bucket] = total. (1 block per bucket,
// thread t handles blocks 2t, 2t+1; int2 write = coalesced.)
__global__ __launch_bounds__(256) void k_bktscan(const int* __restrict__ cnt_bm,
                                                 int* __restrict__ locoff_tm,
                                                 int* __restrict__ bktot, int nbk) {
  int g = blockIdx.x, t = threadIdx.x;
  int c0 = cnt_bm[(size_t)(2 * t) * nbk + g];
  int c1 = cnt_bm[(size_t)(2 * t + 1) * nbk + g];
  __shared__ int sh[256];
  int s = c0 + c1;
  sh[t] = s;
  __syncthreads();
  for (int off = 1; off < 256; off <<= 1) {
    int v = (t >= off) ? sh[t - off] : 0;
    __syncthreads();
    if (t >= off) sh[t] += v;
    __syncthreads();
  }
  int excl = sh[t] - s;
  ((int2*)(locoff_tm + (size_t)g * NEB))[t] = make_int2(excl, excl + c0);
  if (t == 255) bktot[g] = sh[255];
}

// Phase B2: single-block exclusive scan of bucket totals -> bucket_base.
__global__ __launch_bounds__(256) void k_topscan(const int* __restrict__ bktot,
                                                 int* __restrict__ bucket_base,
                                                 int nbk, int E,
                                                 int* __restrict__ row_ptr, int N) {
  __shared__ int sums[256];
  int t = threadIdx.x;
  int vals[4];
  int s = 0;
#pragma unroll
  for (int j = 0; j < 4; ++j) {
    int idx = t * 4 + j;
    vals[j] = (idx < nbk) ? bktot[idx] : 0;
    s += vals[j];
  }
  sums[t] = s;
  __syncthreads();
  for (int off = 1; off < 256; off <<= 1) {
    int v = (t >= off) ? sums[t - off] : 0;
    __syncthreads();
    if (t >= off) sums[t] += v;
    __syncthreads();
  }
  int run = sums[t] - s;
#pragma unroll
  for (int j = 0; j < 4; ++j) {
    int idx = t * 4 + j;
    if (idx < nbk) bucket_base[idx] = run;
    run += vals[j];
  }
  if (t == 0) { bucket_base[nbk] = E; row_ptr[N] = E; }
}

// Phase C: placement. LDS cursors seeded with exact global offsets — zero
// global atomics; per-(block,bucket) writes are contiguous ~64B runs.
__global__ __launch_bounds__(256) void k_eplace(const int* __restrict__ src,
                                                const int* __restrict__ dst,
                                                const int* __restrict__ bucket_base,
                                                const int* __restrict__ locoff_tm,
                                                int2* __restrict__ bedge,
                                                int E, int chunk, int nbk) {
  __shared__ int lptr[1024];
  int blk = blockIdx.x, t = threadIdx.x;
  for (int i = t; i < nbk; i += 256)
    lptr[i] = bucket_base[i] + locoff_tm[(size_t)i * NEB + blk];
  __syncthreads();
  int e0 = blk * chunk, e1 = min(e0 + chunk, E);
  for (int e = e0 + t; e < e1; e += 256) {
    int d = dst[e];
    int b = d >> BSHIFT;
    int p = atomicAdd(&lptr[b], 1);  // LDS atomic
    bedge[p] = make_int2(src[e], d);
  }
}

// Phase D: one block per bucket — LDS deg/scan/cursor over 256 local nodes,
// coalesced row_ptr write, col scatter confined to a block-private ~16KB
// window (single CU -> lines fill completely; worked in round 7).
__global__ __launch_bounds__(256) void k_bcsr2(const int2* __restrict__ bedge,
                                               const int* __restrict__ bucket_base,
                                               int* __restrict__ row_ptr,
                                               int* __restrict__ col, int N) {
  int g = blockIdx.x, t = threadIdx.x;
  int beg = bucket_base[g], end = bucket_base[g + 1];
  __shared__ int deg[BSIZE];
  __shared__ int sh[BSIZE];
  __shared__ int cur[BSIZE];
  deg[t] = 0;
  __syncthreads();
  for (int i = beg + t; i < end; i += 256)
    atomicAdd(&deg[bedge[i].y & (BSIZE - 1)], 1);
  __syncthreads();
  int s = deg[t];
  sh[t] = s;
  __syncthreads();
  for (int off = 1; off < 256; off <<= 1) {
    int v = (t >= off) ? sh[t - off] : 0;
    __syncthreads();
    if (t >= off) sh[t] += v;
    __syncthreads();
  }
  int ex = beg + sh[t] - s;
  int node = g * BSIZE + t;
  if (node < N) row_ptr[node] = ex;
  cur[t] = ex;
  __syncthreads();
  for (int i = beg + t; i < end; i += 256) {
    int2 ed = bedge[i];
    int p = atomicAdd(&cur[ed.y & (BSIZE - 1)], 1);
    col[p] = ed.x;
  }
}

// ---------------- fp32 -> bf16 convert (layer-0 X) ----------------
__global__ __launch_bounds__(256) void k_f2bf(const float4* __restrict__ in,
                                              ushort4* __restrict__ out, int n4) {
  int i = blockIdx.x * 256 + threadIdx.x;
  if (i < n4) {
    float4 v = in[i];
    ushort4 o;
    o.x = f2bf(v.x); o.y = f2bf(v.y); o.z = f2bf(v.z); o.w = f2bf(v.w);
    out[i] = o;
  }
}

// ---------------- W pre-swizzle into MFMA A-operand fragment layout ----------------
__global__ __launch_bounds__(256) void k_wswz(const float* __restrict__ Wl,
                                              const float* __restrict__ Wr,
                                              unsigned short* __restrict__ out) {
  int idx = blockIdx.x * 256 + threadIdx.x;  // 0..32767
  int j = idx & 7, lane = (idx >> 3) & 63, ct = (idx >> 9) & 15, ks = idx >> 13;
  int k = ks * 32 + (lane >> 4) * 8 + j;
  int c = ct * 16 + (lane & 15);
  float v = (c < 128) ? Wl[k * 128 + c] : Wr[k * 128 + (c - 128)];
  out[idx] = f2bf(v);
}

// ---------------- MFMA dual GEMM, D=128, bf16 in/out, fp32 accum ----------------
__global__ __launch_bounds__(256) void gemm128_mfma(
    const unsigned short* __restrict__ Xb, const unsigned short* __restrict__ Wswz,
    const float* __restrict__ bias,
    unsigned short* __restrict__ outL, unsigned short* __restrict__ outR, int M) {
  int wave = threadIdx.x >> 6, lane = threadIdx.x & 63;
  int quad = lane >> 4, n16 = lane & 15;
  int row = blockIdx.x * 64 + wave * 16 + n16;
  int row_ld = min(row, M - 1);
  bool ok = row < M;

  short8 xf[4];
  const unsigned short* xp = Xb + (size_t)row_ld * 128 + quad * 8;
#pragma unroll
  for (int ks = 0; ks < 4; ++ks) xf[ks] = *(const short8*)(xp + ks * 32);

  size_t obase = (size_t)row * 128;
#pragma unroll 4
  for (int ct = 0; ct < 16; ++ct) {
    f32x4 acc = {0.f, 0.f, 0.f, 0.f};
    const unsigned short* wp = Wswz + (size_t)(ct * 64 + lane) * 8;
#pragma unroll
    for (int ks = 0; ks < 4; ++ks) {
      short8 wf = *(const short8*)(wp + ks * 8192);
      acc = __builtin_amdgcn_mfma_f32_16x16x32_bf16(wf, xf[ks], acc, 0, 0, 0);
    }
    int colh = (ct & 7) * 16 + quad * 4;
    if (ct < 8) {
      if (ok) {
        ushort4 o;
        o.x = f2bf(acc[0]); o.y = f2bf(acc[1]); o.z = f2bf(acc[2]); o.w = f2bf(acc[3]);
        *(ushort4*)(outL + obase + colh) = o;
      }
    } else {
      float4 bv = *(const float4*)(bias + colh);
      if (ok) {
        ushort4 o;
        o.x = f2bf(acc[0] + bv.x); o.y = f2bf(acc[1] + bv.y);
        o.z = f2bf(acc[2] + bv.z); o.w = f2bf(acc[3] + bv.w);
        *(ushort4*)(outR + obase + colh) = o;
      }
    }
  }
}

// ---------------- dual GEMM, D=40 (layer 2) — bf16 in, fp32 compute ----------------
__global__ __launch_bounds__(256) void dual_gemm40(
    const unsigned short* __restrict__ Xb, const float* __restrict__ Wl,
    const float* __restrict__ Wr, const float* __restrict__ b,
    unsigned short* __restrict__ tlb, float* __restrict__ outR, int M) {
  __shared__ float Xs[128 * 64];
  __shared__ float Wsc[32 * 80];
  int row0 = blockIdx.x * 64;
  int tid = threadIdx.x;

  {
    int rr = tid & 63;
    int kq0 = tid >> 6;
    int row = min(row0 + rr, M - 1);
    const unsigned short* xrow = Xb + (size_t)row * 128;
#pragma unroll
    for (int kq = kq0; kq < 16; kq += 4) {
      uint4 raw = *(const uint4*)(xrow + kq * 8);
      int k = kq * 8;
      Xs[(k + 0) * 64 + rr] = bflo(raw.x);
      Xs[(k + 1) * 64 + rr] = bfhi(raw.x);
      Xs[(k + 2) * 64 + rr] = bflo(raw.y);
      Xs[(k + 3) * 64 + rr] = bfhi(raw.y);
      Xs[(k + 4) * 64 + rr] = bflo(raw.z);
      Xs[(k + 5) * 64 + rr] = bfhi(raw.z);
      Xs[(k + 6) * 64 + rr] = bflo(raw.w);
      Xs[(k + 7) * 64 + rr] = bfhi(raw.w);
    }
  }

  float acc[4][5];
#pragma unroll
  for (int i = 0; i < 4; ++i)
#pragma unroll
    for (int j = 0; j < 5; ++j) acc[i][j] = 0.f;

  int tx = tid & 15, ty = tid >> 4;
  int r0 = ty * 4;
  int c0 = tx * 5;

  for (int kk = 0; kk < 128; kk += 32) {
    __syncthreads();
    for (int i = tid; i < 32 * 80; i += 256) {
      int k = i / 80, c = i - k * 80;
      Wsc[i] = (c < 40) ? Wl[(kk + k) * 40 + c] : Wr[(kk + k) * 40 + (c - 40)];
    }
    __syncthreads();
#pragma unroll 8
    for (int k = 0; k < 32; ++k) {
      const float4 xv = *(const float4*)&Xs[(kk + k) * 64 + r0];
      float xf[4] = {xv.x, xv.y, xv.z, xv.w};
      const float* wp = &Wsc[k * 80 + c0];
#pragma unroll
      for (int j = 0; j < 5; ++j) {
        float w = wp[j];
#pragma unroll
        for (int i = 0; i < 4; ++i) acc[i][j] = fmaf(xf[i], w, acc[i][j]);
      }
    }
  }

#pragma unroll
  for (int j = 0; j < 5; ++j) {
    int c80 = c0 + j;
    bool right = c80 >= 40;
    int c = right ? (c80 - 40) : c80;
    float bias = right ? b[c] : 0.f;
#pragma unroll
    for (int i = 0; i < 4; ++i) {
      int row = row0 + r0 + i;
      if (row < M) {
        if (right) outR[(size_t)row * 40 + c] = acc[i][j] + bias;
        else       tlb[(size_t)row * 64 + c] = f2bf(acc[i][j]);
      }
    }
  }
}

// ---------------- aggregation D=128 (bf16 payload), fused deg_inv+add+relu ----------------
__global__ __launch_bounds__(256) void agg128b(
    const unsigned short* __restrict__ xl, const unsigned short* __restrict__ xr,
    const int* __restrict__ row_ptr, const int* __restrict__ col,
    unsigned short* __restrict__ h, int Nn) {
  int wave = threadIdx.x >> 6;
  int lane = threadIdx.x & 63;
  int n = blockIdx.x * 4 + wave;
  if (n >= Nn) return;
  int beg = row_ptr[n], end = row_ptr[n + 1];
  const unsigned* xlu = (const unsigned*)xl;
  float ax0 = 0.f, ay0 = 0.f, ax1 = 0.f, ay1 = 0.f;
  float ax2 = 0.f, ay2 = 0.f, ax3 = 0.f, ay3 = 0.f;
  int e = beg;
  for (; e + 4 <= end; e += 4) {
    unsigned u0 = xlu[(size_t)col[e] * 64 + lane];
    unsigned u1 = xlu[(size_t)col[e + 1] * 64 + lane];
    unsigned u2 = xlu[(size_t)col[e + 2] * 64 + lane];
    unsigned u3 = xlu[(size_t)col[e + 3] * 64 + lane];
    ax0 += bflo(u0); ay0 += bfhi(u0);
    ax1 += bflo(u1); ay1 += bfhi(u1);
    ax2 += bflo(u2); ay2 += bfhi(u2);
    ax3 += bflo(u3); ay3 += bfhi(u3);
  }
  for (; e < end; ++e) {
    unsigned u = xlu[(size_t)col[e] * 64 + lane];
    ax0 += bflo(u); ay0 += bfhi(u);
  }
  float ax = (ax0 + ax1) + (ax2 + ax3);
  float ay = (ay0 + ay1) + (ay2 + ay3);
  float di = 1.0f / (float)max(end - beg, 1);
  unsigned ur = ((const unsigned*)xr)[(size_t)n * 64 + lane];
  float ox = fmaxf(fmaf(ax, di, bflo(ur)), 0.f);
  float oy = fmaxf(fmaf(ay, di, bfhi(ur)), 0.f);
  ((unsigned*)h)[(size_t)n * 64 + lane] = pack2(ox, oy);
}

// ---------------- aggregation D=40 (bf16 padded-64 payload) + log_softmax ----------------
__global__ __launch_bounds__(256) void agg40_lsm(
    const unsigned short* __restrict__ tlb, const float* __restrict__ tr,
    const int* __restrict__ row_ptr, const int* __restrict__ col,
    float* __restrict__ out, int Nn) {
  int wave = threadIdx.x >> 6;
  int lane = threadIdx.x & 63;
  int half = lane >> 5;
  int l32 = lane & 31;
  int n = blockIdx.x * 4 + wave;
  if (n >= Nn) return;
  int beg = row_ptr[n], end = row_ptr[n + 1];
  const unsigned* tlu = (const unsigned*)tlb;
  float a0x = 0.f, a0y = 0.f, a1x = 0.f, a1y = 0.f;
  int e = beg + half;
  for (; e + 2 < end; e += 4) {
    unsigned u0 = tlu[(size_t)col[e] * 32 + l32];
    unsigned u1 = tlu[(size_t)col[e + 2] * 32 + l32];
    a0x += bflo(u0); a0y += bfhi(u0);
    a1x += bflo(u1); a1y += bfhi(u1);
  }
  if (e < end) {
    unsigned u = tlu[(size_t)col[e] * 32 + l32];
    a0x += bflo(u); a0y += bfhi(u);
  }
  float ax = a0x + a1x;
  float ay = a0y + a1y;
  ax += __shfl_xor(ax, 32);
  ay += __shfl_xor(ay, 32);
  bool valid = l32 < 20;
  float di = 1.0f / (float)max(end - beg, 1);
  float2 rv = valid ? ((const float2*)(tr + (size_t)n * 40))[l32]
                    : make_float2(0.f, 0.f);
  float v0 = valid ? fmaf(ax, di, rv.x) : -INFINITY;
  float v1 = valid ? fmaf(ay, di, rv.y) : -INFINITY;
  float m = fmaxf(v0, v1);
#pragma unroll
  for (int off = 32; off; off >>= 1) m = fmaxf(m, __shfl_xor(m, off));
  float ex = valid ? (expf(v0 - m) + expf(v1 - m)) : 0.f;
  float ssum = ex;
#pragma unroll
  for (int off = 32; off; off >>= 1) ssum += __shfl_xor(ssum, off);
  ssum *= 0.5f;  // both halves contributed identical totals
  float lg = logf(ssum);
  if (half == 0 && valid) {
    float2 o;
    o.x = (v0 - m) - lg;
    o.y = (v1 - m) - lg;
    *(float2*)(out + (size_t)n * 40 + 2 * l32) = o;
  }
}

// ---------------- launcher ----------------

extern "C" void kernel_launch(void* const* d_in, const int* in_sizes, int n_in,
                              void* d_out, int out_size, void* d_ws, size_t ws_size,
                              hipStream_t stream) {
  const float* x   = (const float*)d_in[0];
  const int*   ei  = (const int*)d_in[1];
  const float* Wl0 = (const float*)d_in[2];
  const float* Wr0 = (const float*)d_in[3];
  const float* b0  = (const float*)d_in[4];
  const float* Wl1 = (const float*)d_in[5];
  const float* Wr1 = (const float*)d_in[6];
  const float* b1  = (const float*)d_in[7];
  const float* Wl2 = (const float*)d_in[8];
  const float* Wr2 = (const float*)d_in[9];
  const float* b2  = (const float*)d_in[10];

  int N = in_sizes[0] / 128;
  int E = in_sizes[1] / 2;
  const int* src = ei;
  const int* dst = ei + E;
  int nbk = (N + BSIZE - 1) / BSIZE;       // 391 buckets of 256 nodes
  int chunk = (E + NEB - 1) / NEB;         // edges per hist/place block

  char* ws = (char*)d_ws;
  size_t off = 0;
  auto alloc = [&](size_t bytes) -> void* {
    void* p = ws + off;
    off += (bytes + 255) & ~(size_t)255;
    return p;
  };
  unsigned short* xb  = (unsigned short*)alloc((size_t)N * 128 * 2);
  unsigned short* gA  = (unsigned short*)alloc((size_t)N * 128 * 2);
  unsigned short* gB  = (unsigned short*)alloc((size_t)N * 128 * 2);
  unsigned short* hC  = (unsigned short*)alloc((size_t)N * 128 * 2);
  unsigned short* tlb = (unsigned short*)alloc((size_t)N * 64 * 2);
  float* tr           = (float*)alloc((size_t)N * 40 * 4);
  int* row_ptr  = (int*)alloc((size_t)(N + 1) * 4);
  int* col      = (int*)alloc((size_t)E * 4);
  int2* bedge   = (int2*)alloc((size_t)E * 8);
  int* cnt_bm   = (int*)alloc((size_t)NEB * nbk * 4);
  int* locoff   = (int*)alloc((size_t)nbk * NEB * 4);
  int* bktot    = (int*)alloc((size_t)nbk * 4);
  int* bbase    = (int*)alloc((size_t)(nbk + 1) * 4);
  unsigned short* wswz0 = (unsigned short*)alloc(32768 * 2);
  unsigned short* wswz1 = (unsigned short*)alloc(32768 * 2);
  (void)ws_size; (void)n_in; (void)out_size;

  hipMemsetAsync(tlb, 0, (size_t)N * 64 * 2, stream);  // zero the 40..63 pad

  // CSR build (no global atomics; all writes block-local or exact-offset)
  k_ehist<<<NEB, 256, 0, stream>>>(dst, cnt_bm, E, chunk, nbk);
  k_bktscan<<<nbk, 256, 0, stream>>>(cnt_bm, locoff, bktot, nbk);
  k_topscan<<<1, 256, 0, stream>>>(bktot, bbase, nbk, E, row_ptr, N);
  k_eplace<<<NEB, 256, 0, stream>>>(src, dst, bbase, locoff, bedge, E, chunk, nbk);
  k_bcsr2<<<nbk, 256, 0, stream>>>(bedge, bbase, row_ptr, col, N);

  int n4 = N * 32;
  k_f2bf<<<(n4 + 255) / 256, 256, 0, stream>>>((const float4*)x, (ushort4*)xb, n4);
  k_wswz<<<128, 256, 0, stream>>>(Wl0, Wr0, wswz0);
  k_wswz<<<128, 256, 0, stream>>>(Wl1, Wr1, wswz1);

  int gg = (N + 63) / 64;
  int nb = (N + 3) / 4;

  // layer 0
  gemm128_mfma<<<gg, 256, 0, stream>>>(xb, wswz0, b0, gA, gB, N);
  agg128b<<<nb, 256, 0, stream>>>(gA, gB, row_ptr, col, hC, N);
  // layer 1
  gemm128_mfma<<<gg, 256, 0, stream>>>(hC, wswz1, b1, gA, gB, N);
  agg128b<<<nb, 256, 0, stream>>>(gA, gB, row_ptr, col, hC, N);
  // layer 2 (40-dim) + log_softmax
  dual_gemm40<<<gg, 256, 0, stream>>>(hC, Wl2, Wr2, b2, tlb, tr, N);
  agg40_lsm<<<nb, 256, 0, stream>>>(tlb, tr, row_ptr, col, (float*)d_out, N);
}

// Round 9
// 531.027 us; speedup vs baseline: 1.7846x; 1.1116x over previous
//
#include <hip/hip_runtime.h>
#include <math.h>

#define THREADS 256
#define BSHIFT 8
#define BSIZE 256   // nodes per bucket
#define NEB 512     // edge blocks for hist/place

typedef short short8 __attribute__((ext_vector_type(8)));
typedef float f32x4 __attribute__((ext_vector_type(4)));

// bf16 helpers (storage = ushort; RNE pack, exact unpack)
__device__ __forceinline__ unsigned short f2bf(float f) {
  unsigned u = __builtin_bit_cast(unsigned, f);
  return (unsigned short)((u + 0x7FFFu + ((u >> 16) & 1u)) >> 16);
}
__device__ __forceinline__ float bflo(unsigned u) {
  return __builtin_bit_cast(float, u << 16);
}
__device__ __forceinline__ float bfhi(unsigned u) {
  return __builtin_bit_cast(float, u & 0xFFFF0000u);
}
__device__ __forceinline__ unsigned pack2(float x, float y) {
  return (unsigned)f2bf(x) | ((unsigned)f2bf(y) << 16);
}

// ---------------- CSR build: two-pass local-offset binning (round-8, works) ----------------

// Phase A: per-block histogram of dst>>BSHIFT. cnt_bm[block*nbk + bucket].
__global__ __launch_bounds__(256) void k_ehist(const int* __restrict__ dst,
                                               int* __restrict__ cnt_bm,
                                               int E, int chunk, int nbk) {
  __shared__ int h[1024];
  int blk = blockIdx.x, t = threadIdx.x;
  for (int i = t; i < nbk; i += 256) h[i] = 0;
  __syncthreads();
  int e0 = blk * chunk, e1 = min(e0 + chunk, E);
  for (int e = e0 + t; e < e1; e += 256) atomicAdd(&h[dst[e] >> BSHIFT], 1);
  __syncthreads();
  for (int i = t; i < nbk; i += 256) cnt_bm[(size_t)blk * nbk + i] = h[i];
}

// Phase B1: per-bucket exclusive scan over the NEB block counts.
__global__ __launch_bounds__(256) void k_bktscan(const int* __restrict__ cnt_bm,
                                                 int* __restrict__ locoff_tm,
                                                 int* __restrict__ bktot, int nbk) {
  int g = blockIdx.x, t = threadIdx.x;
  int c0 = cnt_bm[(size_t)(2 * t) * nbk + g];
  int c1 = cnt_bm[(size_t)(2 * t + 1) * nbk + g];
  __shared__ int sh[256];
  int s = c0 + c1;
  sh[t] = s;
  __syncthreads();
  for (int off = 1; off < 256; off <<= 1) {
    int v = (t >= off) ? sh[t - off] : 0;
    __syncthreads();
    if (t >= off) sh[t] += v;
    __syncthreads();
  }
  int excl = sh[t] - s;
  ((int2*)(locoff_tm + (size_t)g * NEB))[t] = make_int2(excl, excl + c0);
  if (t == 255) bktot[g] = sh[255];
}

// Phase B2: single-block exclusive scan of bucket totals -> bucket_base.
__global__ __launch_bounds__(256) void k_topscan(const int* __restrict__ bktot,
                                                 int* __restrict__ bucket_base,
                                                 int nbk, int E,
                                                 int* __restrict__ row_ptr, int N) {
  __shared__ int sums[256];
  int t = threadIdx.x;
  int vals[4];
  int s = 0;
#pragma unroll
  for (int j = 0; j < 4; ++j) {
    int idx = t * 4 + j;
    vals[j] = (idx < nbk) ? bktot[idx] : 0;
    s += vals[j];
  }
  sums[t] = s;
  __syncthreads();
  for (int off = 1; off < 256; off <<= 1) {
    int v = (t >= off) ? sums[t - off] : 0;
    __syncthreads();
    if (t >= off) sums[t] += v;
    __syncthreads();
  }
  int run = sums[t] - s;
#pragma unroll
  for (int j = 0; j < 4; ++j) {
    int idx = t * 4 + j;
    if (idx < nbk) bucket_base[idx] = run;
    run += vals[j];
  }
  if (t == 0) { bucket_base[nbk] = E; row_ptr[N] = E; }
}

// Phase C: placement via LDS cursors seeded with exact global offsets.
__global__ __launch_bounds__(256) void k_eplace(const int* __restrict__ src,
                                                const int* __restrict__ dst,
                                                const int* __restrict__ bucket_base,
                                                const int* __restrict__ locoff_tm,
                                                int2* __restrict__ bedge,
                                                int E, int chunk, int nbk) {
  __shared__ int lptr[1024];
  int blk = blockIdx.x, t = threadIdx.x;
  for (int i = t; i < nbk; i += 256)
    lptr[i] = bucket_base[i] + locoff_tm[(size_t)i * NEB + blk];
  __syncthreads();
  int e0 = blk * chunk, e1 = min(e0 + chunk, E);
  for (int e = e0 + t; e < e1; e += 256) {
    int d = dst[e];
    int b = d >> BSHIFT;
    int p = atomicAdd(&lptr[b], 1);  // LDS atomic
    bedge[p] = make_int2(src[e], d);
  }
}

// Phase D: one block per bucket — LDS deg/scan/cursor, block-private col window.
__global__ __launch_bounds__(256) void k_bcsr2(const int2* __restrict__ bedge,
                                               const int* __restrict__ bucket_base,
                                               int* __restrict__ row_ptr,
                                               int* __restrict__ col, int N) {
  int g = blockIdx.x, t = threadIdx.x;
  int beg = bucket_base[g], end = bucket_base[g + 1];
  __shared__ int deg[BSIZE];
  __shared__ int sh[BSIZE];
  __shared__ int cur[BSIZE];
  deg[t] = 0;
  __syncthreads();
  for (int i = beg + t; i < end; i += 256)
    atomicAdd(&deg[bedge[i].y & (BSIZE - 1)], 1);
  __syncthreads();
  int s = deg[t];
  sh[t] = s;
  __syncthreads();
  for (int off = 1; off < 256; off <<= 1) {
    int v = (t >= off) ? sh[t - off] : 0;
    __syncthreads();
    if (t >= off) sh[t] += v;
    __syncthreads();
  }
  int ex = beg + sh[t] - s;
  int node = g * BSIZE + t;
  if (node < N) row_ptr[node] = ex;
  cur[t] = ex;
  __syncthreads();
  for (int i = beg + t; i < end; i += 256) {
    int2 ed = bedge[i];
    int p = atomicAdd(&cur[ed.y & (BSIZE - 1)], 1);
    col[p] = ed.x;
  }
}

// ---------------- fp32 -> bf16 convert (layer-0 X) ----------------
__global__ __launch_bounds__(256) void k_f2bf(const float4* __restrict__ in,
                                              ushort4* __restrict__ out, int n4) {
  int i = blockIdx.x * 256 + threadIdx.x;
  if (i < n4) {
    float4 v = in[i];
    ushort4 o;
    o.x = f2bf(v.x); o.y = f2bf(v.y); o.z = f2bf(v.z); o.w = f2bf(v.w);
    out[i] = o;
  }
}

// ---------------- W pre-swizzle into MFMA A-operand fragment layout ----------------
// Operand swap: A-op = W, B-op = X, so in C/D: (lane&15)=X-row, quad*4+reg=W-col.
// A-op layout (16x16x32): lane holds A[m=lane&15][k=quad*8+j], j=0..7.
__global__ __launch_bounds__(256) void k_wswz(const float* __restrict__ Wl,
                                              const float* __restrict__ Wr,
                                              unsigned short* __restrict__ out) {
  int idx = blockIdx.x * 256 + threadIdx.x;  // 0..32767
  int j = idx & 7, lane = (idx >> 3) & 63, ct = (idx >> 9) & 15, ks = idx >> 13;
  int k = ks * 32 + (lane >> 4) * 8 + j;
  int c = ct * 16 + (lane & 15);
  float v = (c < 128) ? Wl[k * 128 + c] : Wr[k * 128 + (c - 128)];
  out[idx] = f2bf(v);
}

// Same swizzle for layer-2's [Wl2|Wr2] (128x80): 5 column tiles, 4 K-chunks.
// idx = ((ks*5 + ct)*64 + lane)*8 + j; 10240 entries = 20KB.
__global__ __launch_bounds__(256) void k_wswz40(const float* __restrict__ Wl,
                                                const float* __restrict__ Wr,
                                                unsigned short* __restrict__ out) {
  int idx = blockIdx.x * 256 + threadIdx.x;  // 0..10239
  int j = idx & 7, lane = (idx >> 3) & 63;
  int tile = idx >> 9;            // ks*5 + ct
  int ct = tile % 5, ks = tile / 5;
  int k = ks * 32 + (lane >> 4) * 8 + j;
  int c = ct * 16 + (lane & 15);
  float v = (c < 40) ? Wl[k * 40 + c] : ((c < 80) ? Wr[k * 40 + (c - 40)] : 0.f);
  out[idx] = f2bf(v);
}

// ---------------- MFMA dual GEMM, D=128, bf16 in/out, fp32 accum ----------------
__global__ __launch_bounds__(256) void gemm128_mfma(
    const unsigned short* __restrict__ Xb, const unsigned short* __restrict__ Wswz,
    const float* __restrict__ bias,
    unsigned short* __restrict__ outL, unsigned short* __restrict__ outR, int M) {
  int wave = threadIdx.x >> 6, lane = threadIdx.x & 63;
  int quad = lane >> 4, n16 = lane & 15;
  int row = blockIdx.x * 64 + wave * 16 + n16;
  int row_ld = min(row, M - 1);
  bool ok = row < M;

  short8 xf[4];
  const unsigned short* xp = Xb + (size_t)row_ld * 128 + quad * 8;
#pragma unroll
  for (int ks = 0; ks < 4; ++ks) xf[ks] = *(const short8*)(xp + ks * 32);

  size_t obase = (size_t)row * 128;
#pragma unroll 4
  for (int ct = 0; ct < 16; ++ct) {
    f32x4 acc = {0.f, 0.f, 0.f, 0.f};
    const unsigned short* wp = Wswz + (size_t)(ct * 64 + lane) * 8;
#pragma unroll
    for (int ks = 0; ks < 4; ++ks) {
      short8 wf = *(const short8*)(wp + ks * 8192);
      acc = __builtin_amdgcn_mfma_f32_16x16x32_bf16(wf, xf[ks], acc, 0, 0, 0);
    }
    int colh = (ct & 7) * 16 + quad * 4;
    if (ct < 8) {
      if (ok) {
        ushort4 o;
        o.x = f2bf(acc[0]); o.y = f2bf(acc[1]); o.z = f2bf(acc[2]); o.w = f2bf(acc[3]);
        *(ushort4*)(outL + obase + colh) = o;
      }
    } else {
      float4 bv = *(const float4*)(bias + colh);
      if (ok) {
        ushort4 o;
        o.x = f2bf(acc[0] + bv.x); o.y = f2bf(acc[1] + bv.y);
        o.z = f2bf(acc[2] + bv.z); o.w = f2bf(acc[3] + bv.w);
        *(ushort4*)(outR + obase + colh) = o;
      }
    }
  }
}

// ---------------- MFMA dual GEMM, D=40 (layer 2) ----------------
// Round-9: replaces the fp32 VALU dual_gemm40 (83us, VALUBusy 37%, MfmaUtil 0,
// 43KB LDS capping occupancy at 25% — same signature dual_gemm128 had before
// its MFMA port). Zero LDS; 20KB W-frag table L2-resident; 20 MFMA/wave.
// Tile-col quad*4 never straddles the L/R boundary (col 40 is quad-aligned in
// tile 2): L side -> bf16 ushort4 into padded tlb, R side -> bias + float4 tr.
__global__ __launch_bounds__(256) void gemm40_mfma(
    const unsigned short* __restrict__ Xb, const unsigned short* __restrict__ Wswz,
    const float* __restrict__ bias,
    unsigned short* __restrict__ tlb, float* __restrict__ tr, int M) {
  int wave = threadIdx.x >> 6, lane = threadIdx.x & 63;
  int quad = lane >> 4, n16 = lane & 15;
  int row = blockIdx.x * 64 + wave * 16 + n16;
  int row_ld = min(row, M - 1);
  bool ok = row < M;

  short8 xf[4];
  const unsigned short* xp = Xb + (size_t)row_ld * 128 + quad * 8;
#pragma unroll
  for (int ks = 0; ks < 4; ++ks) xf[ks] = *(const short8*)(xp + ks * 32);

#pragma unroll
  for (int ct = 0; ct < 5; ++ct) {
    f32x4 acc = {0.f, 0.f, 0.f, 0.f};
    const unsigned short* wp = Wswz + (size_t)(ct * 64 + lane) * 8;
#pragma unroll
    for (int ks = 0; ks < 4; ++ks) {
      short8 wf = *(const short8*)(wp + (size_t)ks * 5 * 64 * 8);
      acc = __builtin_amdgcn_mfma_f32_16x16x32_bf16(wf, xf[ks], acc, 0, 0, 0);
    }
    int cglob = ct * 16 + quad * 4;
    if (!ok) continue;
    if (cglob < 40) {
      ushort4 o;
      o.x = f2bf(acc[0]); o.y = f2bf(acc[1]); o.z = f2bf(acc[2]); o.w = f2bf(acc[3]);
      *(ushort4*)(tlb + (size_t)row * 64 + cglob) = o;
    } else {
      int c = cglob - 40;
      float4 bv = *(const float4*)(bias + c);
      float4 o;
      o.x = acc[0] + bv.x; o.y = acc[1] + bv.y;
      o.z = acc[2] + bv.z; o.w = acc[3] + bv.w;
      *(float4*)(tr + (size_t)row * 40 + c) = o;
    }
  }
}

// ---------------- aggregation D=128 (bf16 payload), fused deg_inv+add+relu ----------------
__global__ __launch_bounds__(256) void agg128b(
    const unsigned short* __restrict__ xl, const unsigned short* __restrict__ xr,
    const int* __restrict__ row_ptr, const int* __restrict__ col,
    unsigned short* __restrict__ h, int Nn) {
  int wave = threadIdx.x >> 6;
  int lane = threadIdx.x & 63;
  int n = blockIdx.x * 4 + wave;
  if (n >= Nn) return;
  int beg = row_ptr[n], end = row_ptr[n + 1];
  const unsigned* xlu = (const unsigned*)xl;
  float ax0 = 0.f, ay0 = 0.f, ax1 = 0.f, ay1 = 0.f;
  float ax2 = 0.f, ay2 = 0.f, ax3 = 0.f, ay3 = 0.f;
  int e = beg;
  for (; e + 4 <= end; e += 4) {
    unsigned u0 = xlu[(size_t)col[e] * 64 + lane];
    unsigned u1 = xlu[(size_t)col[e + 1] * 64 + lane];
    unsigned u2 = xlu[(size_t)col[e + 2] * 64 + lane];
    unsigned u3 = xlu[(size_t)col[e + 3] * 64 + lane];
    ax0 += bflo(u0); ay0 += bfhi(u0);
    ax1 += bflo(u1); ay1 += bfhi(u1);
    ax2 += bflo(u2); ay2 += bfhi(u2);
    ax3 += bflo(u3); ay3 += bfhi(u3);
  }
  for (; e < end; ++e) {
    unsigned u = xlu[(size_t)col[e] * 64 + lane];
    ax0 += bflo(u); ay0 += bfhi(u);
  }
  float ax = (ax0 + ax1) + (ax2 + ax3);
  float ay = (ay0 + ay1) + (ay2 + ay3);
  float di = 1.0f / (float)max(end - beg, 1);
  unsigned ur = ((const unsigned*)xr)[(size_t)n * 64 + lane];
  float ox = fmaxf(fmaf(ax, di, bflo(ur)), 0.f);
  float oy = fmaxf(fmaf(ay, di, bfhi(ur)), 0.f);
  ((unsigned*)h)[(size_t)n * 64 + lane] = pack2(ox, oy);
}

// ---------------- aggregation D=40 (bf16 padded-64 payload) + log_softmax ----------------
__global__ __launch_bounds__(256) void agg40_lsm(
    const unsigned short* __restrict__ tlb, const float* __restrict__ tr,
    const int* __restrict__ row_ptr, const int* __restrict__ col,
    float* __restrict__ out, int Nn) {
  int wave = threadIdx.x >> 6;
  int lane = threadIdx.x & 63;
  int half = lane >> 5;
  int l32 = lane & 31;
  int n = blockIdx.x * 4 + wave;
  if (n >= Nn) return;
  int beg = row_ptr[n], end = row_ptr[n + 1];
  const unsigned* tlu = (const unsigned*)tlb;
  float a0x = 0.f, a0y = 0.f, a1x = 0.f, a1y = 0.f;
  int e = beg + half;
  for (; e + 2 < end; e += 4) {
    unsigned u0 = tlu[(size_t)col[e] * 32 + l32];
    unsigned u1 = tlu[(size_t)col[e + 2] * 32 + l32];
    a0x += bflo(u0); a0y += bfhi(u0);
    a1x += bflo(u1); a1y += bfhi(u1);
  }
  if (e < end) {
    unsigned u = tlu[(size_t)col[e] * 32 + l32];
    a0x += bflo(u); a0y += bfhi(u);
  }
  float ax = a0x + a1x;
  float ay = a0y + a1y;
  ax += __shfl_xor(ax, 32);
  ay += __shfl_xor(ay, 32);
  bool valid = l32 < 20;
  float di = 1.0f / (float)max(end - beg, 1);
  float2 rv = valid ? ((const float2*)(tr + (size_t)n * 40))[l32]
                    : make_float2(0.f, 0.f);
  float v0 = valid ? fmaf(ax, di, rv.x) : -INFINITY;
  float v1 = valid ? fmaf(ay, di, rv.y) : -INFINITY;
  float m = fmaxf(v0, v1);
#pragma unroll
  for (int off = 32; off; off >>= 1) m = fmaxf(m, __shfl_xor(m, off));
  float ex = valid ? (expf(v0 - m) + expf(v1 - m)) : 0.f;
  float ssum = ex;
#pragma unroll
  for (int off = 32; off; off >>= 1) ssum += __shfl_xor(ssum, off);
  ssum *= 0.5f;  // both halves contributed identical totals
  float lg = logf(ssum);
  if (half == 0 && valid) {
    float2 o;
    o.x = (v0 - m) - lg;
    o.y = (v1 - m) - lg;
    *(float2*)(out + (size_t)n * 40 + 2 * l32) = o;
  }
}

// ---------------- launcher ----------------

extern "C" void kernel_launch(void* const* d_in, const int* in_sizes, int n_in,
                              void* d_out, int out_size, void* d_ws, size_t ws_size,
                              hipStream_t stream) {
  const float* x   = (const float*)d_in[0];
  const int*   ei  = (const int*)d_in[1];
  const float* Wl0 = (const float*)d_in[2];
  const float* Wr0 = (const float*)d_in[3];
  const float* b0  = (const float*)d_in[4];
  const float* Wl1 = (const float*)d_in[5];
  const float* Wr1 = (const float*)d_in[6];
  const float* b1  = (const float*)d_in[7];
  const float* Wl2 = (const float*)d_in[8];
  const float* Wr2 = (const float*)d_in[9];
  const float* b2  = (const float*)d_in[10];

  int N = in_sizes[0] / 128;
  int E = in_sizes[1] / 2;
  const int* src = ei;
  const int* dst = ei + E;
  int nbk = (N + BSIZE - 1) / BSIZE;       // 391 buckets of 256 nodes
  int chunk = (E + NEB - 1) / NEB;         // edges per hist/place block

  char* ws = (char*)d_ws;
  size_t off = 0;
  auto alloc = [&](size_t bytes) -> void* {
    void* p = ws + off;
    off += (bytes + 255) & ~(size_t)255;
    return p;
  };
  unsigned short* xb  = (unsigned short*)alloc((size_t)N * 128 * 2);
  unsigned short* gA  = (unsigned short*)alloc((size_t)N * 128 * 2);
  unsigned short* gB  = (unsigned short*)alloc((size_t)N * 128 * 2);
  unsigned short* hC  = (unsigned short*)alloc((size_t)N * 128 * 2);
  unsigned short* tlb = (unsigned short*)alloc((size_t)N * 64 * 2);
  float* tr           = (float*)alloc((size_t)N * 40 * 4);
  int* row_ptr  = (int*)alloc((size_t)(N + 1) * 4);
  int* col      = (int*)alloc((size_t)E * 4);
  int2* bedge   = (int2*)alloc((size_t)E * 8);
  int* cnt_bm   = (int*)alloc((size_t)NEB * nbk * 4);
  int* locoff   = (int*)alloc((size_t)nbk * NEB * 4);
  int* bktot    = (int*)alloc((size_t)nbk * 4);
  int* bbase    = (int*)alloc((size_t)(nbk + 1) * 4);
  unsigned short* wswz0 = (unsigned short*)alloc(32768 * 2);
  unsigned short* wswz1 = (unsigned short*)alloc(32768 * 2);
  unsigned short* wswz2 = (unsigned short*)alloc(10240 * 2);
  (void)ws_size; (void)n_in; (void)out_size;

  hipMemsetAsync(tlb, 0, (size_t)N * 64 * 2, stream);  // zero the 40..63 pad

  // CSR build (no global atomics; all writes block-local or exact-offset)
  k_ehist<<<NEB, 256, 0, stream>>>(dst, cnt_bm, E, chunk, nbk);
  k_bktscan<<<nbk, 256, 0, stream>>>(cnt_bm, locoff, bktot, nbk);
  k_topscan<<<1, 256, 0, stream>>>(bktot, bbase, nbk, E, row_ptr, N);
  k_eplace<<<NEB, 256, 0, stream>>>(src, dst, bbase, locoff, bedge, E, chunk, nbk);
  k_bcsr2<<<nbk, 256, 0, stream>>>(bedge, bbase, row_ptr, col, N);

  int n4 = N * 32;
  k_f2bf<<<(n4 + 255) / 256, 256, 0, stream>>>((const float4*)x, (ushort4*)xb, n4);
  k_wswz<<<128, 256, 0, stream>>>(Wl0, Wr0, wswz0);
  k_wswz<<<128, 256, 0, stream>>>(Wl1, Wr1, wswz1);
  k_wswz40<<<40, 256, 0, stream>>>(Wl2, Wr2, wswz2);

  int gg = (N + 63) / 64;
  int nb = (N + 3) / 4;

  // layer 0
  gemm128_mfma<<<gg, 256, 0, stream>>>(xb, wswz0, b0, gA, gB, N);
  agg128b<<<nb, 256, 0, stream>>>(gA, gB, row_ptr, col, hC, N);
  // layer 1
  gemm128_mfma<<<gg, 256, 0, stream>>>(hC, wswz1, b1, gA, gB, N);
  agg128b<<<nb, 256, 0, stream>>>(gA, gB, row_ptr, col, hC, N);
  // layer 2 (40-dim) + log_softmax
  gemm40_mfma<<<gg, 256, 0, stream>>>(hC, wswz2, b2, tlb, tr, N);
  agg40_lsm<<<nb, 256, 0, stream>>>(tlb, tr, row_ptr, col, (float*)d_out, N);
}

// Round 10
// 515.920 us; speedup vs baseline: 1.8369x; 1.0293x over previous
//
#include <hip/hip_runtime.h>
#include <math.h>

#define THREADS 256
#define BSHIFT 8
#define BSIZE 256   // nodes per bucket
#define NEB 512     // edge blocks for hist/place

typedef short short8 __attribute__((ext_vector_type(8)));
typedef float f32x4 __attribute__((ext_vector_type(4)));

// bf16 helpers (storage = ushort; RNE pack, exact unpack)
__device__ __forceinline__ unsigned short f2bf(float f) {
  unsigned u = __builtin_bit_cast(unsigned, f);
  return (unsigned short)((u + 0x7FFFu + ((u >> 16) & 1u)) >> 16);
}
__device__ __forceinline__ float bflo(unsigned u) {
  return __builtin_bit_cast(float, u << 16);
}
__device__ __forceinline__ float bfhi(unsigned u) {
  return __builtin_bit_cast(float, u & 0xFFFF0000u);
}
__device__ __forceinline__ unsigned pack2(float x, float y) {
  return (unsigned)f2bf(x) | ((unsigned)f2bf(y) << 16);
}

// ---------------- CSR build: two-pass local-offset binning (round-8, works) ----------------

__global__ __launch_bounds__(256) void k_ehist(const int* __restrict__ dst,
                                               int* __restrict__ cnt_bm,
                                               int E, int chunk, int nbk) {
  __shared__ int h[1024];
  int blk = blockIdx.x, t = threadIdx.x;
  for (int i = t; i < nbk; i += 256) h[i] = 0;
  __syncthreads();
  int e0 = blk * chunk, e1 = min(e0 + chunk, E);
  for (int e = e0 + t; e < e1; e += 256) atomicAdd(&h[dst[e] >> BSHIFT], 1);
  __syncthreads();
  for (int i = t; i < nbk; i += 256) cnt_bm[(size_t)blk * nbk + i] = h[i];
}

__global__ __launch_bounds__(256) void k_bktscan(const int* __restrict__ cnt_bm,
                                                 int* __restrict__ locoff_tm,
                                                 int* __restrict__ bktot, int nbk) {
  int g = blockIdx.x, t = threadIdx.x;
  int c0 = cnt_bm[(size_t)(2 * t) * nbk + g];
  int c1 = cnt_bm[(size_t)(2 * t + 1) * nbk + g];
  __shared__ int sh[256];
  int s = c0 + c1;
  sh[t] = s;
  __syncthreads();
  for (int off = 1; off < 256; off <<= 1) {
    int v = (t >= off) ? sh[t - off] : 0;
    __syncthreads();
    if (t >= off) sh[t] += v;
    __syncthreads();
  }
  int excl = sh[t] - s;
  ((int2*)(locoff_tm + (size_t)g * NEB))[t] = make_int2(excl, excl + c0);
  if (t == 255) bktot[g] = sh[255];
}

__global__ __launch_bounds__(256) void k_topscan(const int* __restrict__ bktot,
                                                 int* __restrict__ bucket_base,
                                                 int nbk, int E,
                                                 int* __restrict__ row_ptr, int N) {
  __shared__ int sums[256];
  int t = threadIdx.x;
  int vals[4];
  int s = 0;
#pragma unroll
  for (int j = 0; j < 4; ++j) {
    int idx = t * 4 + j;
    vals[j] = (idx < nbk) ? bktot[idx] : 0;
    s += vals[j];
  }
  sums[t] = s;
  __syncthreads();
  for (int off = 1; off < 256; off <<= 1) {
    int v = (t >= off) ? sums[t - off] : 0;
    __syncthreads();
    if (t >= off) sums[t] += v;
    __syncthreads();
  }
  int run = sums[t] - s;
#pragma unroll
  for (int j = 0; j < 4; ++j) {
    int idx = t * 4 + j;
    if (idx < nbk) bucket_base[idx] = run;
    run += vals[j];
  }
  if (t == 0) { bucket_base[nbk] = E; row_ptr[N] = E; }
}

__global__ __launch_bounds__(256) void k_eplace(const int* __restrict__ src,
                                                const int* __restrict__ dst,
                                                const int* __restrict__ bucket_base,
                                                const int* __restrict__ locoff_tm,
                                                int2* __restrict__ bedge,
                                                int E, int chunk, int nbk) {
  __shared__ int lptr[1024];
  int blk = blockIdx.x, t = threadIdx.x;
  for (int i = t; i < nbk; i += 256)
    lptr[i] = bucket_base[i] + locoff_tm[(size_t)i * NEB + blk];
  __syncthreads();
  int e0 = blk * chunk, e1 = min(e0 + chunk, E);
  for (int e = e0 + t; e < e1; e += 256) {
    int d = dst[e];
    int b = d >> BSHIFT;
    int p = atomicAdd(&lptr[b], 1);  // LDS atomic
    bedge[p] = make_int2(src[e], d);
  }
}

__global__ __launch_bounds__(256) void k_bcsr2(const int2* __restrict__ bedge,
                                               const int* __restrict__ bucket_base,
                                               int* __restrict__ row_ptr,
                                               int* __restrict__ col, int N) {
  int g = blockIdx.x, t = threadIdx.x;
  int beg = bucket_base[g], end = bucket_base[g + 1];
  __shared__ int deg[BSIZE];
  __shared__ int sh[BSIZE];
  __shared__ int cur[BSIZE];
  deg[t] = 0;
  __syncthreads();
  for (int i = beg + t; i < end; i += 256)
    atomicAdd(&deg[bedge[i].y & (BSIZE - 1)], 1);
  __syncthreads();
  int s = deg[t];
  sh[t] = s;
  __syncthreads();
  for (int off = 1; off < 256; off <<= 1) {
    int v = (t >= off) ? sh[t - off] : 0;
    __syncthreads();
    if (t >= off) sh[t] += v;
    __syncthreads();
  }
  int ex = beg + sh[t] - s;
  int node = g * BSIZE + t;
  if (node < N) row_ptr[node] = ex;
  cur[t] = ex;
  __syncthreads();
  for (int i = beg + t; i < end; i += 256) {
    int2 ed = bedge[i];
    int p = atomicAdd(&cur[ed.y & (BSIZE - 1)], 1);
    col[p] = ed.x;
  }
}

// ---------------- fp32 -> bf16 convert (layer-0 X) ----------------
__global__ __launch_bounds__(256) void k_f2bf(const float4* __restrict__ in,
                                              ushort4* __restrict__ out, int n4) {
  int i = blockIdx.x * 256 + threadIdx.x;
  if (i < n4) {
    float4 v = in[i];
    ushort4 o;
    o.x = f2bf(v.x); o.y = f2bf(v.y); o.z = f2bf(v.z); o.w = f2bf(v.w);
    out[i] = o;
  }
}

// ---------------- W pre-swizzle into MFMA A-operand fragment layout ----------------
__global__ __launch_bounds__(256) void k_wswz(const float* __restrict__ Wl,
                                              const float* __restrict__ Wr,
                                              unsigned short* __restrict__ out) {
  int idx = blockIdx.x * 256 + threadIdx.x;  // 0..32767
  int j = idx & 7, lane = (idx >> 3) & 63, ct = (idx >> 9) & 15, ks = idx >> 13;
  int k = ks * 32 + (lane >> 4) * 8 + j;
  int c = ct * 16 + (lane & 15);
  float v = (c < 128) ? Wl[k * 128 + c] : Wr[k * 128 + (c - 128)];
  out[idx] = f2bf(v);
}

__global__ __launch_bounds__(256) void k_wswz40(const float* __restrict__ Wl,
                                                const float* __restrict__ Wr,
                                                unsigned short* __restrict__ out) {
  int idx = blockIdx.x * 256 + threadIdx.x;  // 0..10239
  int j = idx & 7, lane = (idx >> 3) & 63;
  int tile = idx >> 9;            // ks*5 + ct
  int ct = tile % 5, ks = tile / 5;
  int k = ks * 32 + (lane >> 4) * 8 + j;
  int c = ct * 16 + (lane & 15);
  float v = (c < 40) ? Wl[k * 40 + c] : ((c < 80) ? Wr[k * 40 + (c - 40)] : 0.f);
  out[idx] = f2bf(v);
}

// ---------------- MFMA dual GEMM, D=128, bf16 in/out, fp32 accum ----------------
__global__ __launch_bounds__(256) void gemm128_mfma(
    const unsigned short* __restrict__ Xb, const unsigned short* __restrict__ Wswz,
    const float* __restrict__ bias,
    unsigned short* __restrict__ outL, unsigned short* __restrict__ outR, int M) {
  int wave = threadIdx.x >> 6, lane = threadIdx.x & 63;
  int quad = lane >> 4, n16 = lane & 15;
  int row = blockIdx.x * 64 + wave * 16 + n16;
  int row_ld = min(row, M - 1);
  bool ok = row < M;

  short8 xf[4];
  const unsigned short* xp = Xb + (size_t)row_ld * 128 + quad * 8;
#pragma unroll
  for (int ks = 0; ks < 4; ++ks) xf[ks] = *(const short8*)(xp + ks * 32);

  size_t obase = (size_t)row * 128;
#pragma unroll 4
  for (int ct = 0; ct < 16; ++ct) {
    f32x4 acc = {0.f, 0.f, 0.f, 0.f};
    const unsigned short* wp = Wswz + (size_t)(ct * 64 + lane) * 8;
#pragma unroll
    for (int ks = 0; ks < 4; ++ks) {
      short8 wf = *(const short8*)(wp + ks * 8192);
      acc = __builtin_amdgcn_mfma_f32_16x16x32_bf16(wf, xf[ks], acc, 0, 0, 0);
    }
    int colh = (ct & 7) * 16 + quad * 4;
    if (ct < 8) {
      if (ok) {
        ushort4 o;
        o.x = f2bf(acc[0]); o.y = f2bf(acc[1]); o.z = f2bf(acc[2]); o.w = f2bf(acc[3]);
        *(ushort4*)(outL + obase + colh) = o;
      }
    } else {
      float4 bv = *(const float4*)(bias + colh);
      if (ok) {
        ushort4 o;
        o.x = f2bf(acc[0] + bv.x); o.y = f2bf(acc[1] + bv.y);
        o.z = f2bf(acc[2] + bv.z); o.w = f2bf(acc[3] + bv.w);
        *(ushort4*)(outR + obase + colh) = o;
      }
    }
  }
}

// ---------------- MFMA dual GEMM, D=40 (layer 2) ----------------
__global__ __launch_bounds__(256) void gemm40_mfma(
    const unsigned short* __restrict__ Xb, const unsigned short* __restrict__ Wswz,
    const float* __restrict__ bias,
    unsigned short* __restrict__ tlb, float* __restrict__ tr, int M) {
  int wave = threadIdx.x >> 6, lane = threadIdx.x & 63;
  int quad = lane >> 4, n16 = lane & 15;
  int row = blockIdx.x * 64 + wave * 16 + n16;
  int row_ld = min(row, M - 1);
  bool ok = row < M;

  short8 xf[4];
  const unsigned short* xp = Xb + (size_t)row_ld * 128 + quad * 8;
#pragma unroll
  for (int ks = 0; ks < 4; ++ks) xf[ks] = *(const short8*)(xp + ks * 32);

#pragma unroll
  for (int ct = 0; ct < 5; ++ct) {
    f32x4 acc = {0.f, 0.f, 0.f, 0.f};
    const unsigned short* wp = Wswz + (size_t)(ct * 64 + lane) * 8;
#pragma unroll
    for (int ks = 0; ks < 4; ++ks) {
      short8 wf = *(const short8*)(wp + (size_t)ks * 5 * 64 * 8);
      acc = __builtin_amdgcn_mfma_f32_16x16x32_bf16(wf, xf[ks], acc, 0, 0, 0);
    }
    int cglob = ct * 16 + quad * 4;
    if (!ok) continue;
    if (cglob < 40) {
      ushort4 o;
      o.x = f2bf(acc[0]); o.y = f2bf(acc[1]); o.z = f2bf(acc[2]); o.w = f2bf(acc[3]);
      *(ushort4*)(tlb + (size_t)row * 64 + cglob) = o;
    } else {
      int c = cglob - 40;
      float4 bv = *(const float4*)(bias + c);
      float4 o;
      o.x = acc[0] + bv.x; o.y = acc[1] + bv.y;
      o.z = acc[2] + bv.z; o.w = acc[3] + bv.w;
      *(float4*)(tr + (size_t)row * 40 + c) = o;
    }
  }
}

// ---------------- aggregation D=128 (bf16), fused deg_inv+add+relu ----------------
// Round-10 rewrite: round-9 version was 74.5us with VGPR=16, VALUBusy 41%,
// 2.97 TB/s — issue/latency-bound signature (1 VMEM instr/edge, 4 in flight).
// Now: half-wave per edge, uint2 (8B)/lane -> 32 lanes cover the 256B row, so
// one VMEM instr serves one edge on each half-wave (2 edges/instr/wave) and
// the main loop keeps 8 edges in flight (4 loads deep x 2 halves). Uniform
// trip count deg>>3 (no wave divergence); stride-2 guarded tail; shfl_xor(32)
// combines halves; half 0 does the epilogue + 8B store. Memory layout
// unchanged — other kernels untouched.
__global__ __launch_bounds__(256) void agg128b(
    const unsigned short* __restrict__ xl, const unsigned short* __restrict__ xr,
    const int* __restrict__ row_ptr, const int* __restrict__ col,
    unsigned short* __restrict__ h, int Nn) {
  int wave = threadIdx.x >> 6;
  int lane = threadIdx.x & 63;
  int pair = lane >> 5;   // which edge of a pair this half-wave gathers
  int l32 = lane & 31;    // uint2 index in the row (channels 4*l32..4*l32+3)
  int n = blockIdx.x * 4 + wave;
  if (n >= Nn) return;
  int beg = row_ptr[n], end = row_ptr[n + 1];
  int deg = end - beg;
  const uint2* xlq = (const uint2*)xl;
  float a0x = 0.f, a0y = 0.f, a0z = 0.f, a0w = 0.f;
  float a1x = 0.f, a1y = 0.f, a1z = 0.f, a1w = 0.f;
  float a2x = 0.f, a2y = 0.f, a2z = 0.f, a2w = 0.f;
  float a3x = 0.f, a3y = 0.f, a3z = 0.f, a3w = 0.f;
  int e = beg + pair;
  // main: 8 edges per iteration (4 per half-wave), uniform trip count
  for (int it = deg >> 3; it > 0; --it, e += 8) {
    uint2 u0 = xlq[(size_t)col[e]     * 32 + l32];
    uint2 u1 = xlq[(size_t)col[e + 2] * 32 + l32];
    uint2 u2 = xlq[(size_t)col[e + 4] * 32 + l32];
    uint2 u3 = xlq[(size_t)col[e + 6] * 32 + l32];
    a0x += bflo(u0.x); a0y += bfhi(u0.x); a0z += bflo(u0.y); a0w += bfhi(u0.y);
    a1x += bflo(u1.x); a1y += bfhi(u1.x); a1z += bflo(u1.y); a1w += bfhi(u1.y);
    a2x += bflo(u2.x); a2y += bfhi(u2.x); a2z += bflo(u2.y); a2w += bfhi(u2.y);
    a3x += bflo(u3.x); a3y += bfhi(u3.x); a3z += bflo(u3.y); a3w += bfhi(u3.y);
  }
  // tail: remaining edges, stride 2 per half-wave
  for (; e < end; e += 2) {
    uint2 u = xlq[(size_t)col[e] * 32 + l32];
    a0x += bflo(u.x); a0y += bfhi(u.x); a0z += bflo(u.y); a0w += bfhi(u.y);
  }
  float ax = (a0x + a1x) + (a2x + a3x);
  float ay = (a0y + a1y) + (a2y + a3y);
  float az = (a0z + a1z) + (a2z + a3z);
  float aw = (a0w + a1w) + (a2w + a3w);
  // combine the two half-wave partials
  ax += __shfl_xor(ax, 32);
  ay += __shfl_xor(ay, 32);
  az += __shfl_xor(az, 32);
  aw += __shfl_xor(aw, 32);
  if (pair == 0) {
    float di = 1.0f / (float)max(deg, 1);
    uint2 r = ((const uint2*)xr)[(size_t)n * 32 + l32];
    float ox = fmaxf(fmaf(ax, di, bflo(r.x)), 0.f);
    float oy = fmaxf(fmaf(ay, di, bfhi(r.x)), 0.f);
    float oz = fmaxf(fmaf(az, di, bflo(r.y)), 0.f);
    float ow = fmaxf(fmaf(aw, di, bfhi(r.y)), 0.f);
    uint2 o;
    o.x = pack2(ox, oy);
    o.y = pack2(oz, ow);
    ((uint2*)h)[(size_t)n * 32 + l32] = o;
  }
}

// ---------------- aggregation D=40 (bf16 padded-64 payload) + log_softmax ----------------
__global__ __launch_bounds__(256) void agg40_lsm(
    const unsigned short* __restrict__ tlb, const float* __restrict__ tr,
    const int* __restrict__ row_ptr, const int* __restrict__ col,
    float* __restrict__ out, int Nn) {
  int wave = threadIdx.x >> 6;
  int lane = threadIdx.x & 63;
  int half = lane >> 5;
  int l32 = lane & 31;
  int n = blockIdx.x * 4 + wave;
  if (n >= Nn) return;
  int beg = row_ptr[n], end = row_ptr[n + 1];
  const unsigned* tlu = (const unsigned*)tlb;
  float a0x = 0.f, a0y = 0.f, a1x = 0.f, a1y = 0.f;
  int e = beg + half;
  for (; e + 2 < end; e += 4) {
    unsigned u0 = tlu[(size_t)col[e] * 32 + l32];
    unsigned u1 = tlu[(size_t)col[e + 2] * 32 + l32];
    a0x += bflo(u0); a0y += bfhi(u0);
    a1x += bflo(u1); a1y += bfhi(u1);
  }
  if (e < end) {
    unsigned u = tlu[(size_t)col[e] * 32 + l32];
    a0x += bflo(u); a0y += bfhi(u);
  }
  float ax = a0x + a1x;
  float ay = a0y + a1y;
  ax += __shfl_xor(ax, 32);
  ay += __shfl_xor(ay, 32);
  bool valid = l32 < 20;
  float di = 1.0f / (float)max(end - beg, 1);
  float2 rv = valid ? ((const float2*)(tr + (size_t)n * 40))[l32]
                    : make_float2(0.f, 0.f);
  float v0 = valid ? fmaf(ax, di, rv.x) : -INFINITY;
  float v1 = valid ? fmaf(ay, di, rv.y) : -INFINITY;
  float m = fmaxf(v0, v1);
#pragma unroll
  for (int off = 32; off; off >>= 1) m = fmaxf(m, __shfl_xor(m, off));
  float ex = valid ? (expf(v0 - m) + expf(v1 - m)) : 0.f;
  float ssum = ex;
#pragma unroll
  for (int off = 32; off; off >>= 1) ssum += __shfl_xor(ssum, off);
  ssum *= 0.5f;  // both halves contributed identical totals
  float lg = logf(ssum);
  if (half == 0 && valid) {
    float2 o;
    o.x = (v0 - m) - lg;
    o.y = (v1 - m) - lg;
    *(float2*)(out + (size_t)n * 40 + 2 * l32) = o;
  }
}

// ---------------- launcher ----------------

extern "C" void kernel_launch(void* const* d_in, const int* in_sizes, int n_in,
                              void* d_out, int out_size, void* d_ws, size_t ws_size,
                              hipStream_t stream) {
  const float* x   = (const float*)d_in[0];
  const int*   ei  = (const int*)d_in[1];
  const float* Wl0 = (const float*)d_in[2];
  const float* Wr0 = (const float*)d_in[3];
  const float* b0  = (const float*)d_in[4];
  const float* Wl1 = (const float*)d_in[5];
  const float* Wr1 = (const float*)d_in[6];
  const float* b1  = (const float*)d_in[7];
  const float* Wl2 = (const float*)d_in[8];
  const float* Wr2 = (const float*)d_in[9];
  const float* b2  = (const float*)d_in[10];

  int N = in_sizes[0] / 128;
  int E = in_sizes[1] / 2;
  const int* src = ei;
  const int* dst = ei + E;
  int nbk = (N + BSIZE - 1) / BSIZE;       // 391 buckets of 256 nodes
  int chunk = (E + NEB - 1) / NEB;         // edges per hist/place block

  char* ws = (char*)d_ws;
  size_t off = 0;
  auto alloc = [&](size_t bytes) -> void* {
    void* p = ws + off;
    off += (bytes + 255) & ~(size_t)255;
    return p;
  };
  unsigned short* xb  = (unsigned short*)alloc((size_t)N * 128 * 2);
  unsigned short* gA  = (unsigned short*)alloc((size_t)N * 128 * 2);
  unsigned short* gB  = (unsigned short*)alloc((size_t)N * 128 * 2);
  unsigned short* hC  = (unsigned short*)alloc((size_t)N * 128 * 2);
  unsigned short* tlb = (unsigned short*)alloc((size_t)N * 64 * 2);
  float* tr           = (float*)alloc((size_t)N * 40 * 4);
  int* row_ptr  = (int*)alloc((size_t)(N + 1) * 4);
  int* col      = (int*)alloc((size_t)E * 4);
  int2* bedge   = (int2*)alloc((size_t)E * 8);
  int* cnt_bm   = (int*)alloc((size_t)NEB * nbk * 4);
  int* locoff   = (int*)alloc((size_t)nbk * NEB * 4);
  int* bktot    = (int*)alloc((size_t)nbk * 4);
  int* bbase    = (int*)alloc((size_t)(nbk + 1) * 4);
  unsigned short* wswz0 = (unsigned short*)alloc(32768 * 2);
  unsigned short* wswz1 = (unsigned short*)alloc(32768 * 2);
  unsigned short* wswz2 = (unsigned short*)alloc(10240 * 2);
  (void)ws_size; (void)n_in; (void)out_size;

  hipMemsetAsync(tlb, 0, (size_t)N * 64 * 2, stream);  // zero the 40..63 pad

  // CSR build (no global atomics; all writes block-local or exact-offset)
  k_ehist<<<NEB, 256, 0, stream>>>(dst, cnt_bm, E, chunk, nbk);
  k_bktscan<<<nbk, 256, 0, stream>>>(cnt_bm, locoff, bktot, nbk);
  k_topscan<<<1, 256, 0, stream>>>(bktot, bbase, nbk, E, row_ptr, N);
  k_eplace<<<NEB, 256, 0, stream>>>(src, dst, bbase, locoff, bedge, E, chunk, nbk);
  k_bcsr2<<<nbk, 256, 0, stream>>>(bedge, bbase, row_ptr, col, N);

  int n4 = N * 32;
  k_f2bf<<<(n4 + 255) / 256, 256, 0, stream>>>((const float4*)x, (ushort4*)xb, n4);
  k_wswz<<<128, 256, 0, stream>>>(Wl0, Wr0, wswz0);
  k_wswz<<<128, 256, 0, stream>>>(Wl1, Wr1, wswz1);
  k_wswz40<<<40, 256, 0, stream>>>(Wl2, Wr2, wswz2);

  int gg = (N + 63) / 64;
  int nb = (N + 3) / 4;

  // layer 0
  gemm128_mfma<<<gg, 256, 0, stream>>>(xb, wswz0, b0, gA, gB, N);
  agg128b<<<nb, 256, 0, stream>>>(gA, gB, row_ptr, col, hC, N);
  // layer 1
  gemm128_mfma<<<gg, 256, 0, stream>>>(hC, wswz1, b1, gA, gB, N);
  agg128b<<<nb, 256, 0, stream>>>(gA, gB, row_ptr, col, hC, N);
  // layer 2 (40-dim) + log_softmax
  gemm40_mfma<<<gg, 256, 0, stream>>>(hC, wswz2, b2, tlb, tr, N);
  agg40_lsm<<<nb, 256, 0, stream>>>(tlb, tr, row_ptr, col, (float*)d_out, N);
}

// Round 11
// 504.774 us; speedup vs baseline: 1.8775x; 1.0221x over previous
//
#include <hip/hip_runtime.h>
#include <math.h>

#define THREADS 256
#define BSHIFT 8
#define BSIZE 256   // nodes per bucket
#define NEB 512     // edge blocks for hist/place

typedef short short8 __attribute__((ext_vector_type(8)));
typedef float f32x4 __attribute__((ext_vector_type(4)));

// bf16 helpers (storage = ushort; RNE pack, exact unpack)
__device__ __forceinline__ unsigned short f2bf(float f) {
  unsigned u = __builtin_bit_cast(unsigned, f);
  return (unsigned short)((u + 0x7FFFu + ((u >> 16) & 1u)) >> 16);
}
__device__ __forceinline__ float bflo(unsigned u) {
  return __builtin_bit_cast(float, u << 16);
}
__device__ __forceinline__ float bfhi(unsigned u) {
  return __builtin_bit_cast(float, u & 0xFFFF0000u);
}
__device__ __forceinline__ unsigned pack2(float x, float y) {
  return (unsigned)f2bf(x) | ((unsigned)f2bf(y) << 16);
}

// ---------------- CSR build: two-pass local-offset binning ----------------
// Round-11: bedge packed to a single int — src<2^17, local node = dst&255
// -> (src<<8)|(dst&255) fits 25 bits. Halves k_eplace write / k_bcsr2 read.

__global__ __launch_bounds__(256) void k_ehist(const int* __restrict__ dst,
                                               int* __restrict__ cnt_bm,
                                               int E, int chunk, int nbk) {
  __shared__ int h[1024];
  int blk = blockIdx.x, t = threadIdx.x;
  for (int i = t; i < nbk; i += 256) h[i] = 0;
  __syncthreads();
  int e0 = blk * chunk, e1 = min(e0 + chunk, E);
  for (int e = e0 + t; e < e1; e += 256) atomicAdd(&h[dst[e] >> BSHIFT], 1);
  __syncthreads();
  for (int i = t; i < nbk; i += 256) cnt_bm[(size_t)blk * nbk + i] = h[i];
}

__global__ __launch_bounds__(256) void k_bktscan(const int* __restrict__ cnt_bm,
                                                 int* __restrict__ locoff_tm,
                                                 int* __restrict__ bktot, int nbk) {
  int g = blockIdx.x, t = threadIdx.x;
  int c0 = cnt_bm[(size_t)(2 * t) * nbk + g];
  int c1 = cnt_bm[(size_t)(2 * t + 1) * nbk + g];
  __shared__ int sh[256];
  int s = c0 + c1;
  sh[t] = s;
  __syncthreads();
  for (int off = 1; off < 256; off <<= 1) {
    int v = (t >= off) ? sh[t - off] : 0;
    __syncthreads();
    if (t >= off) sh[t] += v;
    __syncthreads();
  }
  int excl = sh[t] - s;
  ((int2*)(locoff_tm + (size_t)g * NEB))[t] = make_int2(excl, excl + c0);
  if (t == 255) bktot[g] = sh[255];
}

__global__ __launch_bounds__(256) void k_topscan(const int* __restrict__ bktot,
                                                 int* __restrict__ bucket_base,
                                                 int nbk, int E,
                                                 int* __restrict__ row_ptr, int N) {
  __shared__ int sums[256];
  int t = threadIdx.x;
  int vals[4];
  int s = 0;
#pragma unroll
  for (int j = 0; j < 4; ++j) {
    int idx = t * 4 + j;
    vals[j] = (idx < nbk) ? bktot[idx] : 0;
    s += vals[j];
  }
  sums[t] = s;
  __syncthreads();
  for (int off = 1; off < 256; off <<= 1) {
    int v = (t >= off) ? sums[t - off] : 0;
    __syncthreads();
    if (t >= off) sums[t] += v;
    __syncthreads();
  }
  int run = sums[t] - s;
#pragma unroll
  for (int j = 0; j < 4; ++j) {
    int idx = t * 4 + j;
    if (idx < nbk) bucket_base[idx] = run;
    run += vals[j];
  }
  if (t == 0) { bucket_base[nbk] = E; row_ptr[N] = E; }
}

__global__ __launch_bounds__(256) void k_eplace(const int* __restrict__ src,
                                                const int* __restrict__ dst,
                                                const int* __restrict__ bucket_base,
                                                const int* __restrict__ locoff_tm,
                                                int* __restrict__ bedge,
                                                int E, int chunk, int nbk) {
  __shared__ int lptr[1024];
  int blk = blockIdx.x, t = threadIdx.x;
  for (int i = t; i < nbk; i += 256)
    lptr[i] = bucket_base[i] + locoff_tm[(size_t)i * NEB + blk];
  __syncthreads();
  int e0 = blk * chunk, e1 = min(e0 + chunk, E);
  for (int e = e0 + t; e < e1; e += 256) {
    int d = dst[e];
    int b = d >> BSHIFT;
    int p = atomicAdd(&lptr[b], 1);  // LDS atomic
    bedge[p] = (src[e] << 8) | (d & (BSIZE - 1));
  }
}

__global__ __launch_bounds__(256) void k_bcsr2(const int* __restrict__ bedge,
                                               const int* __restrict__ bucket_base,
                                               int* __restrict__ row_ptr,
                                               int* __restrict__ col, int N) {
  int g = blockIdx.x, t = threadIdx.x;
  int beg = bucket_base[g], end = bucket_base[g + 1];
  __shared__ int deg[BSIZE];
  __shared__ int sh[BSIZE];
  __shared__ int cur[BSIZE];
  deg[t] = 0;
  __syncthreads();
  for (int i = beg + t; i < end; i += 256)
    atomicAdd(&deg[bedge[i] & (BSIZE - 1)], 1);
  __syncthreads();
  int s = deg[t];
  sh[t] = s;
  __syncthreads();
  for (int off = 1; off < 256; off <<= 1) {
    int v = (t >= off) ? sh[t - off] : 0;
    __syncthreads();
    if (t >= off) sh[t] += v;
    __syncthreads();
  }
  int ex = beg + sh[t] - s;
  int node = g * BSIZE + t;
  if (node < N) row_ptr[node] = ex;
  cur[t] = ex;
  __syncthreads();
  for (int i = beg + t; i < end; i += 256) {
    int ed = bedge[i];
    int p = atomicAdd(&cur[ed & (BSIZE - 1)], 1);
    col[p] = ed >> 8;  // value < 2^25, positive
  }
}

// ---------------- fp32 -> bf16 convert (layer-0 X) ----------------
__global__ __launch_bounds__(256) void k_f2bf(const float4* __restrict__ in,
                                              ushort4* __restrict__ out, int n4) {
  int i = blockIdx.x * 256 + threadIdx.x;
  if (i < n4) {
    float4 v = in[i];
    ushort4 o;
    o.x = f2bf(v.x); o.y = f2bf(v.y); o.z = f2bf(v.z); o.w = f2bf(v.w);
    out[i] = o;
  }
}

// ---------------- W pre-swizzle into MFMA A-operand fragment layout ----------------
__global__ __launch_bounds__(256) void k_wswz(const float* __restrict__ Wl,
                                              const float* __restrict__ Wr,
                                              unsigned short* __restrict__ out) {
  int idx = blockIdx.x * 256 + threadIdx.x;  // 0..32767
  int j = idx & 7, lane = (idx >> 3) & 63, ct = (idx >> 9) & 15, ks = idx >> 13;
  int k = ks * 32 + (lane >> 4) * 8 + j;
  int c = ct * 16 + (lane & 15);
  float v = (c < 128) ? Wl[k * 128 + c] : Wr[k * 128 + (c - 128)];
  out[idx] = f2bf(v);
}

__global__ __launch_bounds__(256) void k_wswz40(const float* __restrict__ Wl,
                                                const float* __restrict__ Wr,
                                                unsigned short* __restrict__ out) {
  int idx = blockIdx.x * 256 + threadIdx.x;  // 0..10239
  int j = idx & 7, lane = (idx >> 3) & 63;
  int tile = idx >> 9;            // ks*5 + ct
  int ct = tile % 5, ks = tile / 5;
  int k = ks * 32 + (lane >> 4) * 8 + j;
  int c = ct * 16 + (lane & 15);
  float v = (c < 40) ? Wl[k * 40 + c] : ((c < 80) ? Wr[k * 40 + (c - 40)] : 0.f);
  out[idx] = f2bf(v);
}

// ---------------- MFMA dual GEMM, D=128, bf16 in/out, fp32 accum ----------------
__global__ __launch_bounds__(256) void gemm128_mfma(
    const unsigned short* __restrict__ Xb, const unsigned short* __restrict__ Wswz,
    const float* __restrict__ bias,
    unsigned short* __restrict__ outL, unsigned short* __restrict__ outR, int M) {
  int wave = threadIdx.x >> 6, lane = threadIdx.x & 63;
  int quad = lane >> 4, n16 = lane & 15;
  int row = blockIdx.x * 64 + wave * 16 + n16;
  int row_ld = min(row, M - 1);
  bool ok = row < M;

  short8 xf[4];
  const unsigned short* xp = Xb + (size_t)row_ld * 128 + quad * 8;
#pragma unroll
  for (int ks = 0; ks < 4; ++ks) xf[ks] = *(const short8*)(xp + ks * 32);

  size_t obase = (size_t)row * 128;
#pragma unroll 4
  for (int ct = 0; ct < 16; ++ct) {
    f32x4 acc = {0.f, 0.f, 0.f, 0.f};
    const unsigned short* wp = Wswz + (size_t)(ct * 64 + lane) * 8;
#pragma unroll
    for (int ks = 0; ks < 4; ++ks) {
      short8 wf = *(const short8*)(wp + ks * 8192);
      acc = __builtin_amdgcn_mfma_f32_16x16x32_bf16(wf, xf[ks], acc, 0, 0, 0);
    }
    int colh = (ct & 7) * 16 + quad * 4;
    if (ct < 8) {
      if (ok) {
        ushort4 o;
        o.x = f2bf(acc[0]); o.y = f2bf(acc[1]); o.z = f2bf(acc[2]); o.w = f2bf(acc[3]);
        *(ushort4*)(outL + obase + colh) = o;
      }
    } else {
      float4 bv = *(const float4*)(bias + colh);
      if (ok) {
        ushort4 o;
        o.x = f2bf(acc[0] + bv.x); o.y = f2bf(acc[1] + bv.y);
        o.z = f2bf(acc[2] + bv.z); o.w = f2bf(acc[3] + bv.w);
        *(ushort4*)(outR + obase + colh) = o;
      }
    }
  }
}

// ---------------- MFMA dual GEMM, D=40 (layer 2) ----------------
__global__ __launch_bounds__(256) void gemm40_mfma(
    const unsigned short* __restrict__ Xb, const unsigned short* __restrict__ Wswz,
    const float* __restrict__ bias,
    unsigned short* __restrict__ tlb, float* __restrict__ tr, int M) {
  int wave = threadIdx.x >> 6, lane = threadIdx.x & 63;
  int quad = lane >> 4, n16 = lane & 15;
  int row = blockIdx.x * 64 + wave * 16 + n16;
  int row_ld = min(row, M - 1);
  bool ok = row < M;

  short8 xf[4];
  const unsigned short* xp = Xb + (size_t)row_ld * 128 + quad * 8;
#pragma unroll
  for (int ks = 0; ks < 4; ++ks) xf[ks] = *(const short8*)(xp + ks * 32);

#pragma unroll
  for (int ct = 0; ct < 5; ++ct) {
    f32x4 acc = {0.f, 0.f, 0.f, 0.f};
    const unsigned short* wp = Wswz + (size_t)(ct * 64 + lane) * 8;
#pragma unroll
    for (int ks = 0; ks < 4; ++ks) {
      short8 wf = *(const short8*)(wp + (size_t)ks * 5 * 64 * 8);
      acc = __builtin_amdgcn_mfma_f32_16x16x32_bf16(wf, xf[ks], acc, 0, 0, 0);
    }
    int cglob = ct * 16 + quad * 4;
    if (!ok) continue;
    if (cglob < 40) {
      ushort4 o;
      o.x = f2bf(acc[0]); o.y = f2bf(acc[1]); o.z = f2bf(acc[2]); o.w = f2bf(acc[3]);
      *(ushort4*)(tlb + (size_t)row * 64 + cglob) = o;
    } else {
      int c = cglob - 40;
      float4 bv = *(const float4*)(bias + c);
      float4 o;
      o.x = acc[0] + bv.x; o.y = acc[1] + bv.y;
      o.z = acc[2] + bv.z; o.w = acc[3] + bv.w;
      *(float4*)(tr + (size_t)row * 40 + c) = o;
    }
  }
}

// ---------------- aggregation D=128 (bf16), fused deg_inv+add+relu ----------------
// Round-10 structure (half-wave/edge, uint2/lane, 8 edges in flight) — kept.
__global__ __launch_bounds__(256) void agg128b(
    const unsigned short* __restrict__ xl, const unsigned short* __restrict__ xr,
    const int* __restrict__ row_ptr, const int* __restrict__ col,
    unsigned short* __restrict__ h, int Nn) {
  int wave = threadIdx.x >> 6;
  int lane = threadIdx.x & 63;
  int pair = lane >> 5;
  int l32 = lane & 31;
  int n = blockIdx.x * 4 + wave;
  if (n >= Nn) return;
  int beg = row_ptr[n], end = row_ptr[n + 1];
  int deg = end - beg;
  const uint2* xlq = (const uint2*)xl;
  float a0x = 0.f, a0y = 0.f, a0z = 0.f, a0w = 0.f;
  float a1x = 0.f, a1y = 0.f, a1z = 0.f, a1w = 0.f;
  float a2x = 0.f, a2y = 0.f, a2z = 0.f, a2w = 0.f;
  float a3x = 0.f, a3y = 0.f, a3z = 0.f, a3w = 0.f;
  int e = beg + pair;
  for (int it = deg >> 3; it > 0; --it, e += 8) {
    uint2 u0 = xlq[(size_t)col[e]     * 32 + l32];
    uint2 u1 = xlq[(size_t)col[e + 2] * 32 + l32];
    uint2 u2 = xlq[(size_t)col[e + 4] * 32 + l32];
    uint2 u3 = xlq[(size_t)col[e + 6] * 32 + l32];
    a0x += bflo(u0.x); a0y += bfhi(u0.x); a0z += bflo(u0.y); a0w += bfhi(u0.y);
    a1x += bflo(u1.x); a1y += bfhi(u1.x); a1z += bflo(u1.y); a1w += bfhi(u1.y);
    a2x += bflo(u2.x); a2y += bfhi(u2.x); a2z += bflo(u2.y); a2w += bfhi(u2.y);
    a3x += bflo(u3.x); a3y += bfhi(u3.x); a3z += bflo(u3.y); a3w += bfhi(u3.y);
  }
  for (; e < end; e += 2) {
    uint2 u = xlq[(size_t)col[e] * 32 + l32];
    a0x += bflo(u.x); a0y += bfhi(u.x); a0z += bflo(u.y); a0w += bfhi(u.y);
  }
  float ax = (a0x + a1x) + (a2x + a3x);
  float ay = (a0y + a1y) + (a2y + a3y);
  float az = (a0z + a1z) + (a2z + a3z);
  float aw = (a0w + a1w) + (a2w + a3w);
  ax += __shfl_xor(ax, 32);
  ay += __shfl_xor(ay, 32);
  az += __shfl_xor(az, 32);
  aw += __shfl_xor(aw, 32);
  if (pair == 0) {
    float di = 1.0f / (float)max(deg, 1);
    uint2 r = ((const uint2*)xr)[(size_t)n * 32 + l32];
    float ox = fmaxf(fmaf(ax, di, bflo(r.x)), 0.f);
    float oy = fmaxf(fmaf(ay, di, bfhi(r.x)), 0.f);
    float oz = fmaxf(fmaf(az, di, bflo(r.y)), 0.f);
    float ow = fmaxf(fmaf(aw, di, bfhi(r.y)), 0.f);
    uint2 o;
    o.x = pack2(ox, oy);
    o.y = pack2(oz, ow);
    ((uint2*)h)[(size_t)n * 32 + l32] = o;
  }
}

// ---------------- aggregation D=40 (bf16 padded-64) + log_softmax ----------------
// Round-11 rewrite: round-10 was 68us, VGPR=12, VALUBusy 54% — same
// issue/latency signature agg128b had. Quarter-wave per edge: 16 lanes x
// uint2 = the 128B row, so one VMEM instr serves 4 edges per wave; 4-deep
// unroll = 16 edges in flight. Combine quarters via shfl_xor(32)+(16);
// softmax reduces over the 16-lane channel dim (all quartets identical).
__global__ __launch_bounds__(256) void agg40_lsm(
    const unsigned short* __restrict__ tlb, const float* __restrict__ tr,
    const int* __restrict__ row_ptr, const int* __restrict__ col,
    float* __restrict__ out, int Nn) {
  int wave = threadIdx.x >> 6;
  int lane = threadIdx.x & 63;
  int qw = lane >> 4;     // edge slot 0..3
  int l16 = lane & 15;    // uint2 index; channels 4*l16..4*l16+3
  int n = blockIdx.x * 4 + wave;
  if (n >= Nn) return;
  int beg = row_ptr[n], end = row_ptr[n + 1];
  int deg = end - beg;
  const uint2* tlq = (const uint2*)tlb;
  float a0x = 0.f, a0y = 0.f, a0z = 0.f, a0w = 0.f;
  float a1x = 0.f, a1y = 0.f, a1z = 0.f, a1w = 0.f;
  float a2x = 0.f, a2y = 0.f, a2z = 0.f, a2w = 0.f;
  float a3x = 0.f, a3y = 0.f, a3z = 0.f, a3w = 0.f;
  int e = beg + qw;
  // main: 16 edges per iteration (4 per quarter-wave), uniform trip count
  for (int it = deg >> 4; it > 0; --it, e += 16) {
    uint2 u0 = tlq[(size_t)col[e]      * 16 + l16];
    uint2 u1 = tlq[(size_t)col[e + 4]  * 16 + l16];
    uint2 u2 = tlq[(size_t)col[e + 8]  * 16 + l16];
    uint2 u3 = tlq[(size_t)col[e + 12] * 16 + l16];
    a0x += bflo(u0.x); a0y += bfhi(u0.x); a0z += bflo(u0.y); a0w += bfhi(u0.y);
    a1x += bflo(u1.x); a1y += bfhi(u1.x); a1z += bflo(u1.y); a1w += bfhi(u1.y);
    a2x += bflo(u2.x); a2y += bfhi(u2.x); a2z += bflo(u2.y); a2w += bfhi(u2.y);
    a3x += bflo(u3.x); a3y += bfhi(u3.x); a3z += bflo(u3.y); a3w += bfhi(u3.y);
  }
  // tail: stride 4 per quarter-wave
  for (; e < end; e += 4) {
    uint2 u = tlq[(size_t)col[e] * 16 + l16];
    a0x += bflo(u.x); a0y += bfhi(u.x); a0z += bflo(u.y); a0w += bfhi(u.y);
  }
  float ax = (a0x + a1x) + (a2x + a3x);
  float ay = (a0y + a1y) + (a2y + a3y);
  float az = (a0z + a1z) + (a2z + a3z);
  float aw = (a0w + a1w) + (a2w + a3w);
  // combine the four quarter-wave partials (after this all lanes identical per l16)
  ax += __shfl_xor(ax, 32); ay += __shfl_xor(ay, 32);
  az += __shfl_xor(az, 32); aw += __shfl_xor(aw, 32);
  ax += __shfl_xor(ax, 16); ay += __shfl_xor(ay, 16);
  az += __shfl_xor(az, 16); aw += __shfl_xor(aw, 16);
  bool valid = l16 < 10;  // channels 4*l16..4*l16+3 < 40
  float di = 1.0f / (float)max(deg, 1);
  float4 rv = valid ? *(const float4*)(tr + (size_t)n * 40 + 4 * l16)
                    : make_float4(0.f, 0.f, 0.f, 0.f);
  float v0 = valid ? fmaf(ax, di, rv.x) : -INFINITY;
  float v1 = valid ? fmaf(ay, di, rv.y) : -INFINITY;
  float v2 = valid ? fmaf(az, di, rv.z) : -INFINITY;
  float v3 = valid ? fmaf(aw, di, rv.w) : -INFINITY;
  float m = fmaxf(fmaxf(v0, v1), fmaxf(v2, v3));
#pragma unroll
  for (int off = 8; off; off >>= 1) m = fmaxf(m, __shfl_xor(m, off));
  float ex = valid ? (expf(v0 - m) + expf(v1 - m) + expf(v2 - m) + expf(v3 - m)) : 0.f;
  float ssum = ex;
#pragma unroll
  for (int off = 8; off; off >>= 1) ssum += __shfl_xor(ssum, off);
  float lg = logf(ssum);
  if (qw == 0 && valid) {
    float4 o;
    o.x = (v0 - m) - lg;
    o.y = (v1 - m) - lg;
    o.z = (v2 - m) - lg;
    o.w = (v3 - m) - lg;
    *(float4*)(out + (size_t)n * 40 + 4 * l16) = o;
  }
}

// ---------------- launcher ----------------

extern "C" void kernel_launch(void* const* d_in, const int* in_sizes, int n_in,
                              void* d_out, int out_size, void* d_ws, size_t ws_size,
                              hipStream_t stream) {
  const float* x   = (const float*)d_in[0];
  const int*   ei  = (const int*)d_in[1];
  const float* Wl0 = (const float*)d_in[2];
  const float* Wr0 = (const float*)d_in[3];
  const float* b0  = (const float*)d_in[4];
  const float* Wl1 = (const float*)d_in[5];
  const float* Wr1 = (const float*)d_in[6];
  const float* b1  = (const float*)d_in[7];
  const float* Wl2 = (const float*)d_in[8];
  const float* Wr2 = (const float*)d_in[9];
  const float* b2  = (const float*)d_in[10];

  int N = in_sizes[0] / 128;
  int E = in_sizes[1] / 2;
  const int* src = ei;
  const int* dst = ei + E;
  int nbk = (N + BSIZE - 1) / BSIZE;       // 391 buckets of 256 nodes
  int chunk = (E + NEB - 1) / NEB;         // edges per hist/place block

  char* ws = (char*)d_ws;
  size_t off = 0;
  auto alloc = [&](size_t bytes) -> void* {
    void* p = ws + off;
    off += (bytes + 255) & ~(size_t)255;
    return p;
  };
  unsigned short* xb  = (unsigned short*)alloc((size_t)N * 128 * 2);
  unsigned short* gA  = (unsigned short*)alloc((size_t)N * 128 * 2);
  unsigned short* gB  = (unsigned short*)alloc((size_t)N * 128 * 2);
  unsigned short* hC  = (unsigned short*)alloc((size_t)N * 128 * 2);
  unsigned short* tlb = (unsigned short*)alloc((size_t)N * 64 * 2);
  float* tr           = (float*)alloc((size_t)N * 40 * 4);
  int* row_ptr  = (int*)alloc((size_t)(N + 1) * 4);
  int* col      = (int*)alloc((size_t)E * 4);
  int* bedge    = (int*)alloc((size_t)E * 4);   // packed (src<<8)|(dst&255)
  int* cnt_bm   = (int*)alloc((size_t)NEB * nbk * 4);
  int* locoff   = (int*)alloc((size_t)nbk * NEB * 4);
  int* bktot    = (int*)alloc((size_t)nbk * 4);
  int* bbase    = (int*)alloc((size_t)(nbk + 1) * 4);
  unsigned short* wswz0 = (unsigned short*)alloc(32768 * 2);
  unsigned short* wswz1 = (unsigned short*)alloc(32768 * 2);
  unsigned short* wswz2 = (unsigned short*)alloc(10240 * 2);
  (void)ws_size; (void)n_in; (void)out_size;

  hipMemsetAsync(tlb, 0, (size_t)N * 64 * 2, stream);  // zero the 40..63 pad

  // CSR build (no global atomics; all writes block-local or exact-offset)
  k_ehist<<<NEB, 256, 0, stream>>>(dst, cnt_bm, E, chunk, nbk);
  k_bktscan<<<nbk, 256, 0, stream>>>(cnt_bm, locoff, bktot, nbk);
  k_topscan<<<1, 256, 0, stream>>>(bktot, bbase, nbk, E, row_ptr, N);
  k_eplace<<<NEB, 256, 0, stream>>>(src, dst, bbase, locoff, bedge, E, chunk, nbk);
  k_bcsr2<<<nbk, 256, 0, stream>>>(bedge, bbase, row_ptr, col, N);

  int n4 = N * 32;
  k_f2bf<<<(n4 + 255) / 256, 256, 0, stream>>>((const float4*)x, (ushort4*)xb, n4);
  k_wswz<<<128, 256, 0, stream>>>(Wl0, Wr0, wswz0);
  k_wswz<<<128, 256, 0, stream>>>(Wl1, Wr1, wswz1);
  k_wswz40<<<40, 256, 0, stream>>>(Wl2, Wr2, wswz2);

  int gg = (N + 63) / 64;
  int nb = (N + 3) / 4;

  // layer 0
  gemm128_mfma<<<gg, 256, 0, stream>>>(xb, wswz0, b0, gA, gB, N);
  agg128b<<<nb, 256, 0, stream>>>(gA, gB, row_ptr, col, hC, N);
  // layer 1
  gemm128_mfma<<<gg, 256, 0, stream>>>(hC, wswz1, b1, gA, gB, N);
  agg128b<<<nb, 256, 0, stream>>>(gA, gB, row_ptr, col, hC, N);
  // layer 2 (40-dim) + log_softmax
  gemm40_mfma<<<gg, 256, 0, stream>>>(hC, wswz2, b2, tlb, tr, N);
  agg40_lsm<<<nb, 256, 0, stream>>>(tlb, tr, row_ptr, col, (float*)d_out, N);
}

// Round 12
// 471.619 us; speedup vs baseline: 2.0094x; 1.0703x over previous
//
#include <hip/hip_runtime.h>
#include <math.h>

#define THREADS 256
#define BSHIFT 8
#define BSIZE 256   // nodes per bucket
#define NEB 512     // edge blocks for hist/place

typedef short short8 __attribute__((ext_vector_type(8)));
typedef float f32x4 __attribute__((ext_vector_type(4)));

// bf16 helpers (storage = ushort; RNE pack, exact unpack)
__device__ __forceinline__ unsigned short f2bf(float f) {
  unsigned u = __builtin_bit_cast(unsigned, f);
  return (unsigned short)((u + 0x7FFFu + ((u >> 16) & 1u)) >> 16);
}
__device__ __forceinline__ float bflo(unsigned u) {
  return __builtin_bit_cast(float, u << 16);
}
__device__ __forceinline__ float bfhi(unsigned u) {
  return __builtin_bit_cast(float, u & 0xFFFF0000u);
}
__device__ __forceinline__ unsigned pack2(float x, float y) {
  return (unsigned)f2bf(x) | ((unsigned)f2bf(y) << 16);
}

// ---------------- CSR build: two-pass local-offset binning ----------------

__global__ __launch_bounds__(256) void k_ehist(const int* __restrict__ dst,
                                               int* __restrict__ cnt_bm,
                                               int E, int chunk, int nbk) {
  __shared__ int h[1024];
  int blk = blockIdx.x, t = threadIdx.x;
  for (int i = t; i < nbk; i += 256) h[i] = 0;
  __syncthreads();
  int e0 = blk * chunk, e1 = min(e0 + chunk, E);
  for (int e = e0 + t; e < e1; e += 256) atomicAdd(&h[dst[e] >> BSHIFT], 1);
  __syncthreads();
  for (int i = t; i < nbk; i += 256) cnt_bm[(size_t)blk * nbk + i] = h[i];
}

__global__ __launch_bounds__(256) void k_bktscan(const int* __restrict__ cnt_bm,
                                                 int* __restrict__ locoff_tm,
                                                 int* __restrict__ bktot, int nbk) {
  int g = blockIdx.x, t = threadIdx.x;
  int c0 = cnt_bm[(size_t)(2 * t) * nbk + g];
  int c1 = cnt_bm[(size_t)(2 * t + 1) * nbk + g];
  __shared__ int sh[256];
  int s = c0 + c1;
  sh[t] = s;
  __syncthreads();
  for (int off = 1; off < 256; off <<= 1) {
    int v = (t >= off) ? sh[t - off] : 0;
    __syncthreads();
    if (t >= off) sh[t] += v;
    __syncthreads();
  }
  int excl = sh[t] - s;
  ((int2*)(locoff_tm + (size_t)g * NEB))[t] = make_int2(excl, excl + c0);
  if (t == 255) bktot[g] = sh[255];
}

__global__ __launch_bounds__(256) void k_topscan(const int* __restrict__ bktot,
                                                 int* __restrict__ bucket_base,
                                                 int nbk, int E,
                                                 int* __restrict__ row_ptr, int N) {
  __shared__ int sums[256];
  int t = threadIdx.x;
  int vals[4];
  int s = 0;
#pragma unroll
  for (int j = 0; j < 4; ++j) {
    int idx = t * 4 + j;
    vals[j] = (idx < nbk) ? bktot[idx] : 0;
    s += vals[j];
  }
  sums[t] = s;
  __syncthreads();
  for (int off = 1; off < 256; off <<= 1) {
    int v = (t >= off) ? sums[t - off] : 0;
    __syncthreads();
    if (t >= off) sums[t] += v;
    __syncthreads();
  }
  int run = sums[t] - s;
#pragma unroll
  for (int j = 0; j < 4; ++j) {
    int idx = t * 4 + j;
    if (idx < nbk) bucket_base[idx] = run;
    run += vals[j];
  }
  if (t == 0) { bucket_base[nbk] = E; row_ptr[N] = E; }
}

__global__ __launch_bounds__(256) void k_eplace(const int* __restrict__ src,
                                                const int* __restrict__ dst,
                                                const int* __restrict__ bucket_base,
                                                const int* __restrict__ locoff_tm,
                                                int* __restrict__ bedge,
                                                int E, int chunk, int nbk) {
  __shared__ int lptr[1024];
  int blk = blockIdx.x, t = threadIdx.x;
  for (int i = t; i < nbk; i += 256)
    lptr[i] = bucket_base[i] + locoff_tm[(size_t)i * NEB + blk];
  __syncthreads();
  int e0 = blk * chunk, e1 = min(e0 + chunk, E);
  for (int e = e0 + t; e < e1; e += 256) {
    int d = dst[e];
    int b = d >> BSHIFT;
    int p = atomicAdd(&lptr[b], 1);  // LDS atomic
    bedge[p] = (src[e] << 8) | (d & (BSIZE - 1));
  }
}

__global__ __launch_bounds__(256) void k_bcsr2(const int* __restrict__ bedge,
                                               const int* __restrict__ bucket_base,
                                               int* __restrict__ row_ptr,
                                               int* __restrict__ col, int N) {
  int g = blockIdx.x, t = threadIdx.x;
  int beg = bucket_base[g], end = bucket_base[g + 1];
  __shared__ int deg[BSIZE];
  __shared__ int sh[BSIZE];
  __shared__ int cur[BSIZE];
  deg[t] = 0;
  __syncthreads();
  for (int i = beg + t; i < end; i += 256)
    atomicAdd(&deg[bedge[i] & (BSIZE - 1)], 1);
  __syncthreads();
  int s = deg[t];
  sh[t] = s;
  __syncthreads();
  for (int off = 1; off < 256; off <<= 1) {
    int v = (t >= off) ? sh[t - off] : 0;
    __syncthreads();
    if (t >= off) sh[t] += v;
    __syncthreads();
  }
  int ex = beg + sh[t] - s;
  int node = g * BSIZE + t;
  if (node < N) row_ptr[node] = ex;
  cur[t] = ex;
  __syncthreads();
  for (int i = beg + t; i < end; i += 256) {
    int ed = bedge[i];
    int p = atomicAdd(&cur[ed & (BSIZE - 1)], 1);
    col[p] = ed >> 8;  // value < 2^25, positive
  }
}

// ---------------- fp32 -> bf16 convert (layer-0 X) ----------------
__global__ __launch_bounds__(256) void k_f2bf(const float4* __restrict__ in,
                                              ushort4* __restrict__ out, int n4) {
  int i = blockIdx.x * 256 + threadIdx.x;
  if (i < n4) {
    float4 v = in[i];
    ushort4 o;
    o.x = f2bf(v.x); o.y = f2bf(v.y); o.z = f2bf(v.z); o.w = f2bf(v.w);
    out[i] = o;
  }
}

// ---------------- W pre-swizzle into MFMA A-operand fragment layout ----------------
__global__ __launch_bounds__(256) void k_wswz(const float* __restrict__ Wl,
                                              const float* __restrict__ Wr,
                                              unsigned short* __restrict__ out) {
  int idx = blockIdx.x * 256 + threadIdx.x;  // 0..32767
  int j = idx & 7, lane = (idx >> 3) & 63, ct = (idx >> 9) & 15, ks = idx >> 13;
  int k = ks * 32 + (lane >> 4) * 8 + j;
  int c = ct * 16 + (lane & 15);
  float v = (c < 128) ? Wl[k * 128 + c] : Wr[k * 128 + (c - 128)];
  out[idx] = f2bf(v);
}

__global__ __launch_bounds__(256) void k_wswz40(const float* __restrict__ Wl,
                                                const float* __restrict__ Wr,
                                                unsigned short* __restrict__ out) {
  int idx = blockIdx.x * 256 + threadIdx.x;  // 0..10239
  int j = idx & 7, lane = (idx >> 3) & 63;
  int tile = idx >> 9;            // ks*5 + ct
  int ct = tile % 5, ks = tile / 5;
  int k = ks * 32 + (lane >> 4) * 8 + j;
  int c = ct * 16 + (lane & 15);
  float v = (c < 40) ? Wl[k * 40 + c] : ((c < 80) ? Wr[k * 40 + (c - 40)] : 0.f);
  out[idx] = f2bf(v);
}

// ---------------- MFMA dual GEMM, D=128, bf16 in/out, fp32 accum ----------------
// Round-12: BM=128 — each wave computes 2 row-groups (r, r+64) sharing every
// W-fragment load. W L2 traffic halves (was 4 waves x 64KB per 64-row block
// = ~400MB total). Grid halves to (N+127)/128.
__global__ __launch_bounds__(256) void gemm128_mfma(
    const unsigned short* __restrict__ Xb, const unsigned short* __restrict__ Wswz,
    const float* __restrict__ bias,
    unsigned short* __restrict__ outL, unsigned short* __restrict__ outR, int M) {
  int wave = threadIdx.x >> 6, lane = threadIdx.x & 63;
  int quad = lane >> 4, n16 = lane & 15;
  int rowA = blockIdx.x * 128 + wave * 16 + n16;
  int rowB = rowA + 64;
  int rA = min(rowA, M - 1), rB = min(rowB, M - 1);
  bool okA = rowA < M, okB = rowB < M;

  short8 xf[4], xg[4];
  const unsigned short* xpA = Xb + (size_t)rA * 128 + quad * 8;
  const unsigned short* xpB = Xb + (size_t)rB * 128 + quad * 8;
#pragma unroll
  for (int ks = 0; ks < 4; ++ks) {
    xf[ks] = *(const short8*)(xpA + ks * 32);
    xg[ks] = *(const short8*)(xpB + ks * 32);
  }

  size_t obA = (size_t)rowA * 128, obB = (size_t)rowB * 128;
#pragma unroll 2
  for (int ct = 0; ct < 16; ++ct) {
    f32x4 accA = {0.f, 0.f, 0.f, 0.f};
    f32x4 accB = {0.f, 0.f, 0.f, 0.f};
    const unsigned short* wp = Wswz + (size_t)(ct * 64 + lane) * 8;
#pragma unroll
    for (int ks = 0; ks < 4; ++ks) {
      short8 wf = *(const short8*)(wp + ks * 8192);
      accA = __builtin_amdgcn_mfma_f32_16x16x32_bf16(wf, xf[ks], accA, 0, 0, 0);
      accB = __builtin_amdgcn_mfma_f32_16x16x32_bf16(wf, xg[ks], accB, 0, 0, 0);
    }
    int colh = (ct & 7) * 16 + quad * 4;
    if (ct < 8) {
      if (okA) {
        ushort4 o;
        o.x = f2bf(accA[0]); o.y = f2bf(accA[1]); o.z = f2bf(accA[2]); o.w = f2bf(accA[3]);
        *(ushort4*)(outL + obA + colh) = o;
      }
      if (okB) {
        ushort4 o;
        o.x = f2bf(accB[0]); o.y = f2bf(accB[1]); o.z = f2bf(accB[2]); o.w = f2bf(accB[3]);
        *(ushort4*)(outL + obB + colh) = o;
      }
    } else {
      float4 bv = *(const float4*)(bias + colh);
      if (okA) {
        ushort4 o;
        o.x = f2bf(accA[0] + bv.x); o.y = f2bf(accA[1] + bv.y);
        o.z = f2bf(accA[2] + bv.z); o.w = f2bf(accA[3] + bv.w);
        *(ushort4*)(outR + obA + colh) = o;
      }
      if (okB) {
        ushort4 o;
        o.x = f2bf(accB[0] + bv.x); o.y = f2bf(accB[1] + bv.y);
        o.z = f2bf(accB[2] + bv.z); o.w = f2bf(accB[3] + bv.w);
        *(ushort4*)(outR + obB + colh) = o;
      }
    }
  }
}

// ---------------- MFMA dual GEMM, D=40 (layer 2) ----------------
__global__ __launch_bounds__(256) void gemm40_mfma(
    const unsigned short* __restrict__ Xb, const unsigned short* __restrict__ Wswz,
    const float* __restrict__ bias,
    unsigned short* __restrict__ tlb, float* __restrict__ tr, int M) {
  int wave = threadIdx.x >> 6, lane = threadIdx.x & 63;
  int quad = lane >> 4, n16 = lane & 15;
  int row = blockIdx.x * 64 + wave * 16 + n16;
  int row_ld = min(row, M - 1);
  bool ok = row < M;

  short8 xf[4];
  const unsigned short* xp = Xb + (size_t)row_ld * 128 + quad * 8;
#pragma unroll
  for (int ks = 0; ks < 4; ++ks) xf[ks] = *(const short8*)(xp + ks * 32);

#pragma unroll
  for (int ct = 0; ct < 5; ++ct) {
    f32x4 acc = {0.f, 0.f, 0.f, 0.f};
    const unsigned short* wp = Wswz + (size_t)(ct * 64 + lane) * 8;
#pragma unroll
    for (int ks = 0; ks < 4; ++ks) {
      short8 wf = *(const short8*)(wp + (size_t)ks * 5 * 64 * 8);
      acc = __builtin_amdgcn_mfma_f32_16x16x32_bf16(wf, xf[ks], acc, 0, 0, 0);
    }
    int cglob = ct * 16 + quad * 4;
    if (!ok) continue;
    if (cglob < 40) {
      ushort4 o;
      o.x = f2bf(acc[0]); o.y = f2bf(acc[1]); o.z = f2bf(acc[2]); o.w = f2bf(acc[3]);
      *(ushort4*)(tlb + (size_t)row * 64 + cglob) = o;
    } else {
      int c = cglob - 40;
      float4 bv = *(const float4*)(bias + c);
      float4 o;
      o.x = acc[0] + bv.x; o.y = acc[1] + bv.y;
      o.z = acc[2] + bv.z; o.w = acc[3] + bv.w;
      *(float4*)(tr + (size_t)row * 40 + c) = o;
    }
  }
}

// ---------------- aggregation D=128 (bf16), fused deg_inv+add+relu ----------------
// At the random-gather floor: 410MB demand / 68us = 6.0 TB/s served (round 11).
__global__ __launch_bounds__(256) void agg128b(
    const unsigned short* __restrict__ xl, const unsigned short* __restrict__ xr,
    const int* __restrict__ row_ptr, const int* __restrict__ col,
    unsigned short* __restrict__ h, int Nn) {
  int wave = threadIdx.x >> 6;
  int lane = threadIdx.x & 63;
  int pair = lane >> 5;
  int l32 = lane & 31;
  int n = blockIdx.x * 4 + wave;
  if (n >= Nn) return;
  int beg = row_ptr[n], end = row_ptr[n + 1];
  int deg = end - beg;
  const uint2* xlq = (const uint2*)xl;
  float a0x = 0.f, a0y = 0.f, a0z = 0.f, a0w = 0.f;
  float a1x = 0.f, a1y = 0.f, a1z = 0.f, a1w = 0.f;
  float a2x = 0.f, a2y = 0.f, a2z = 0.f, a2w = 0.f;
  float a3x = 0.f, a3y = 0.f, a3z = 0.f, a3w = 0.f;
  int e = beg + pair;
  for (int it = deg >> 3; it > 0; --it, e += 8) {
    uint2 u0 = xlq[(size_t)col[e]     * 32 + l32];
    uint2 u1 = xlq[(size_t)col[e + 2] * 32 + l32];
    uint2 u2 = xlq[(size_t)col[e + 4] * 32 + l32];
    uint2 u3 = xlq[(size_t)col[e + 6] * 32 + l32];
    a0x += bflo(u0.x); a0y += bfhi(u0.x); a0z += bflo(u0.y); a0w += bfhi(u0.y);
    a1x += bflo(u1.x); a1y += bfhi(u1.x); a1z += bflo(u1.y); a1w += bfhi(u1.y);
    a2x += bflo(u2.x); a2y += bfhi(u2.x); a2z += bflo(u2.y); a2w += bfhi(u2.y);
    a3x += bflo(u3.x); a3y += bfhi(u3.x); a3z += bflo(u3.y); a3w += bfhi(u3.y);
  }
  for (; e < end; e += 2) {
    uint2 u = xlq[(size_t)col[e] * 32 + l32];
    a0x += bflo(u.x); a0y += bfhi(u.x); a0z += bflo(u.y); a0w += bfhi(u.y);
  }
  float ax = (a0x + a1x) + (a2x + a3x);
  float ay = (a0y + a1y) + (a2y + a3y);
  float az = (a0z + a1z) + (a2z + a3z);
  float aw = (a0w + a1w) + (a2w + a3w);
  ax += __shfl_xor(ax, 32);
  ay += __shfl_xor(ay, 32);
  az += __shfl_xor(az, 32);
  aw += __shfl_xor(aw, 32);
  if (pair == 0) {
    float di = 1.0f / (float)max(deg, 1);
    uint2 r = ((const uint2*)xr)[(size_t)n * 32 + l32];
    float ox = fmaxf(fmaf(ax, di, bflo(r.x)), 0.f);
    float oy = fmaxf(fmaf(ay, di, bfhi(r.x)), 0.f);
    float oz = fmaxf(fmaf(az, di, bflo(r.y)), 0.f);
    float ow = fmaxf(fmaf(aw, di, bfhi(r.y)), 0.f);
    uint2 o;
    o.x = pack2(ox, oy);
    o.y = pack2(oz, ow);
    ((uint2*)h)[(size_t)n * 32 + l32] = o;
  }
}

// ---------------- aggregation D=40 (bf16 padded-64) + log_softmax ----------------
// Round-12: eighth-wave per edge — 8 lanes x uint4 (16B) cover the 128B row,
// so one VMEM instr serves 8 edges per wave (2x fewer instrs than round-11's
// quarter-wave); 2-deep main loop keeps 16 edges in flight at deg~16.
// Pad channels 40..63 are read as poison (memset dropped) but provably
// discarded: invalid lanes contribute -INF to max and 0 to the exp-sum.
__global__ __launch_bounds__(256) void agg40_lsm(
    const unsigned short* __restrict__ tlb, const float* __restrict__ tr,
    const int* __restrict__ row_ptr, const int* __restrict__ col,
    float* __restrict__ out, int Nn) {
  int wave = threadIdx.x >> 6;
  int lane = threadIdx.x & 63;
  int ew = lane >> 3;    // edge slot 0..7
  int l8 = lane & 7;     // uint4 index; channels 8*l8 .. 8*l8+7
  int n = blockIdx.x * 4 + wave;
  if (n >= Nn) return;
  int beg = row_ptr[n], end = row_ptr[n + 1];
  int deg = end - beg;
  const uint4* tlq = (const uint4*)tlb;
  float a0[8], a1[8];
#pragma unroll
  for (int j = 0; j < 8; ++j) { a0[j] = 0.f; a1[j] = 0.f; }
  int e = beg + ew;
  // main: 16 edges per iteration (2 per eighth-wave slot)
  for (int it = deg >> 4; it > 0; --it, e += 16) {
    uint4 u0 = tlq[(size_t)col[e] * 8 + l8];
    uint4 u1 = tlq[(size_t)col[e + 8] * 8 + l8];
    a0[0] += bflo(u0.x); a0[1] += bfhi(u0.x); a0[2] += bflo(u0.y); a0[3] += bfhi(u0.y);
    a0[4] += bflo(u0.z); a0[5] += bfhi(u0.z); a0[6] += bflo(u0.w); a0[7] += bfhi(u0.w);
    a1[0] += bflo(u1.x); a1[1] += bfhi(u1.x); a1[2] += bflo(u1.y); a1[3] += bfhi(u1.y);
    a1[4] += bflo(u1.z); a1[5] += bfhi(u1.z); a1[6] += bflo(u1.w); a1[7] += bfhi(u1.w);
  }
  // tail: stride 8 per slot
  for (; e < end; e += 8) {
    uint4 u = tlq[(size_t)col[e] * 8 + l8];
    a0[0] += bflo(u.x); a0[1] += bfhi(u.x); a0[2] += bflo(u.y); a0[3] += bfhi(u.y);
    a0[4] += bflo(u.z); a0[5] += bfhi(u.z); a0[6] += bflo(u.w); a0[7] += bfhi(u.w);
  }
  float v[8];
#pragma unroll
  for (int j = 0; j < 8; ++j) {
    float t = a0[j] + a1[j];
    t += __shfl_xor(t, 32);
    t += __shfl_xor(t, 16);
    t += __shfl_xor(t, 8);
    v[j] = t;
  }
  bool valid = l8 < 5;  // channels 8*l8..8*l8+7 < 40
  float di = 1.0f / (float)max(deg, 1);
  float4 r0 = valid ? *(const float4*)(tr + (size_t)n * 40 + 8 * l8)
                    : make_float4(0.f, 0.f, 0.f, 0.f);
  float4 r1 = valid ? *(const float4*)(tr + (size_t)n * 40 + 8 * l8 + 4)
                    : make_float4(0.f, 0.f, 0.f, 0.f);
  float rb[8] = {r0.x, r0.y, r0.z, r0.w, r1.x, r1.y, r1.z, r1.w};
  float vv[8];
#pragma unroll
  for (int j = 0; j < 8; ++j) vv[j] = valid ? fmaf(v[j], di, rb[j]) : -INFINITY;
  float m = vv[0];
#pragma unroll
  for (int j = 1; j < 8; ++j) m = fmaxf(m, vv[j]);
#pragma unroll
  for (int off = 4; off; off >>= 1) m = fmaxf(m, __shfl_xor(m, off));
  float ex = 0.f;
  if (valid) {
#pragma unroll
    for (int j = 0; j < 8; ++j) ex += expf(vv[j] - m);
  }
  float ssum = ex;
#pragma unroll
  for (int off = 4; off; off >>= 1) ssum += __shfl_xor(ssum, off);
  float lg = logf(ssum);
  if (ew == 0 && valid) {
    float4 o0, o1;
    o0.x = (vv[0] - m) - lg; o0.y = (vv[1] - m) - lg;
    o0.z = (vv[2] - m) - lg; o0.w = (vv[3] - m) - lg;
    o1.x = (vv[4] - m) - lg; o1.y = (vv[5] - m) - lg;
    o1.z = (vv[6] - m) - lg; o1.w = (vv[7] - m) - lg;
    *(float4*)(out + (size_t)n * 40 + 8 * l8) = o0;
    *(float4*)(out + (size_t)n * 40 + 8 * l8 + 4) = o1;
  }
}

// ---------------- launcher ----------------

extern "C" void kernel_launch(void* const* d_in, const int* in_sizes, int n_in,
                              void* d_out, int out_size, void* d_ws, size_t ws_size,
                              hipStream_t stream) {
  const float* x   = (const float*)d_in[0];
  const int*   ei  = (const int*)d_in[1];
  const float* Wl0 = (const float*)d_in[2];
  const float* Wr0 = (const float*)d_in[3];
  const float* b0  = (const float*)d_in[4];
  const float* Wl1 = (const float*)d_in[5];
  const float* Wr1 = (const float*)d_in[6];
  const float* b1  = (const float*)d_in[7];
  const float* Wl2 = (const float*)d_in[8];
  const float* Wr2 = (const float*)d_in[9];
  const float* b2  = (const float*)d_in[10];

  int N = in_sizes[0] / 128;
  int E = in_sizes[1] / 2;
  const int* src = ei;
  const int* dst = ei + E;
  int nbk = (N + BSIZE - 1) / BSIZE;       // 391 buckets of 256 nodes
  int chunk = (E + NEB - 1) / NEB;         // edges per hist/place block

  char* ws = (char*)d_ws;
  size_t off = 0;
  auto alloc = [&](size_t bytes) -> void* {
    void* p = ws + off;
    off += (bytes + 255) & ~(size_t)255;
    return p;
  };
  unsigned short* xb  = (unsigned short*)alloc((size_t)N * 128 * 2);
  unsigned short* gA  = (unsigned short*)alloc((size_t)N * 128 * 2);
  unsigned short* gB  = (unsigned short*)alloc((size_t)N * 128 * 2);
  unsigned short* hC  = (unsigned short*)alloc((size_t)N * 128 * 2);
  unsigned short* tlb = (unsigned short*)alloc((size_t)N * 64 * 2);
  float* tr           = (float*)alloc((size_t)N * 40 * 4);
  int* row_ptr  = (int*)alloc((size_t)(N + 1) * 4);
  int* col      = (int*)alloc((size_t)E * 4);
  int* bedge    = (int*)alloc((size_t)E * 4);   // packed (src<<8)|(dst&255)
  int* cnt_bm   = (int*)alloc((size_t)NEB * nbk * 4);
  int* locoff   = (int*)alloc((size_t)nbk * NEB * 4);
  int* bktot    = (int*)alloc((size_t)nbk * 4);
  int* bbase    = (int*)alloc((size_t)(nbk + 1) * 4);
  unsigned short* wswz0 = (unsigned short*)alloc(32768 * 2);
  unsigned short* wswz1 = (unsigned short*)alloc(32768 * 2);
  unsigned short* wswz2 = (unsigned short*)alloc(10240 * 2);
  (void)ws_size; (void)n_in; (void)out_size;

  // CSR build (no global atomics; all writes block-local or exact-offset)
  k_ehist<<<NEB, 256, 0, stream>>>(dst, cnt_bm, E, chunk, nbk);
  k_bktscan<<<nbk, 256, 0, stream>>>(cnt_bm, locoff, bktot, nbk);
  k_topscan<<<1, 256, 0, stream>>>(bktot, bbase, nbk, E, row_ptr, N);
  k_eplace<<<NEB, 256, 0, stream>>>(src, dst, bbase, locoff, bedge, E, chunk, nbk);
  k_bcsr2<<<nbk, 256, 0, stream>>>(bedge, bbase, row_ptr, col, N);

  int n4 = N * 32;
  k_f2bf<<<(n4 + 255) / 256, 256, 0, stream>>>((const float4*)x, (ushort4*)xb, n4);
  k_wswz<<<128, 256, 0, stream>>>(Wl0, Wr0, wswz0);
  k_wswz<<<128, 256, 0, stream>>>(Wl1, Wr1, wswz1);
  k_wswz40<<<40, 256, 0, stream>>>(Wl2, Wr2, wswz2);

  int gg128 = (N + 127) / 128;
  int gg = (N + 63) / 64;
  int nb = (N + 3) / 4;

  // layer 0
  gemm128_mfma<<<gg128, 256, 0, stream>>>(xb, wswz0, b0, gA, gB, N);
  agg128b<<<nb, 256, 0, stream>>>(gA, gB, row_ptr, col, hC, N);
  // layer 1
  gemm128_mfma<<<gg128, 256, 0, stream>>>(hC, wswz1, b1, gA, gB, N);
  agg128b<<<nb, 256, 0, stream>>>(gA, gB, row_ptr, col, hC, N);
  // layer 2 (40-dim) + log_softmax
  gemm40_mfma<<<gg, 256, 0, stream>>>(hC, wswz2, b2, tlb, tr, N);
  agg40_lsm<<<nb, 256, 0, stream>>>(tlb, tr, row_ptr, col, (float*)d_out, N);
}